// Round 15
// baseline (2098.582 us; speedup 1.0000x reference)
//
#include <hip/hip_runtime.h>
#include <math.h>

// Problem constants (ResidualVQ: B=8, N=4096, D=512, C=1024, Q=8)
#define B_   8
#define N_   4096
#define D_   512
#define C_   1024
#define Q_   8
#define ROWS (B_ * N_)   // 32768 token rows

#define TAU  1.0f        // rescue margin; 1-term approx err rms ~0.07-0.1 sigma_r
#define RCH  8           // rows per rescue chunk

typedef __attribute__((ext_vector_type(8))) short bf16x8;
typedef __attribute__((ext_vector_type(4))) float f32x4;

#define MF(a, b, c) __builtin_amdgcn_mfma_f32_16x16x32_bf16(a, b, c, 0, 0, 0)

// round-to-nearest-even f32 -> bf16 (bits)
__device__ __forceinline__ unsigned short bf16rn(float f) {
    unsigned int u = __builtin_bit_cast(unsigned int, f);
    return (unsigned short)((u + 0x7fffu + ((u >> 16) & 1u)) >> 16);
}
// LDS byte offset for tile [row][32 bf16], XOR-swizzled (<=2-way conflicts)
__device__ __forceinline__ int swzoff(int row, int q) {
    return row * 64 + ((q ^ ((row >> 1) & 3)) << 4);
}
// async global->LDS, 16B per lane. LDS dest wave-uniform+lane*16; global src per-lane.
__device__ __forceinline__ void gload16(const void* g, void* l) {
    __builtin_amdgcn_global_load_lds(
        (const __attribute__((address_space(1))) void*)g,
        (__attribute__((address_space(3))) void*)l, 16, 0, 0);
}

// -------------------------------------------------------------------------
// f32 -> bf16 hi (codebooks once per call; x at stage 0)
__global__ __launch_bounds__(256)
void conv_hi_kernel(const float* __restrict__ src, unsigned short* __restrict__ hi) {
    const int i4 = blockIdx.x * 256 + threadIdx.x;
    float4 v = ((const float4*)src)[i4];
    ushort4 h;
    h.x = bf16rn(v.x); h.y = bf16rn(v.y); h.z = bf16rn(v.z); h.w = bf16rn(v.w);
    ((ushort4*)hi)[i4] = h;
}

// ||e||^2 for every code of every stage (exact f32)
__global__ __launch_bounds__(256)
void code_norms_kernel(const float* __restrict__ cb, float* __restrict__ norms) {
    const int code = blockIdx.x * 4 + (threadIdx.x >> 6);
    const int lane = threadIdx.x & 63;
    const float* p = cb + (size_t)code * D_;
    float s = 0.f;
    #pragma unroll
    for (int d = lane * 4; d < D_; d += 256) {
        float4 v = *(const float4*)(p + d);
        s += v.x * v.x + v.y * v.y + v.z * v.z + v.w * v.w;
    }
    #pragma unroll
    for (int m = 1; m < 64; m <<= 1) s += __shfl_xor(s, m);
    if (lane == 0) norms[code] = s;
}

// codebook [q][c][d] -> cbT [q][d][c]  (once per call; coalesced rescue loads)
__global__ __launch_bounds__(256)
void cb_transpose_kernel(const float* __restrict__ cb, float* __restrict__ cbT) {
    __shared__ float tile[64][65];
    const int q = blockIdx.z;
    const int dBase = blockIdx.x * 64;
    const int cBase = blockIdx.y * 64;
    const int tc = threadIdx.x & 63;
    const int tr = threadIdx.x >> 6;   // 0..3
    const float* src = cb + (size_t)q * C_ * D_;
    float* dst = cbT + (size_t)q * D_ * C_;
    #pragma unroll
    for (int i = 0; i < 16; ++i) {
        const int c = tr + 4 * i;
        tile[c][tc] = src[(size_t)(cBase + c) * D_ + dBase + tc];
    }
    __syncthreads();
    #pragma unroll
    for (int i = 0; i < 16; ++i) {
        const int d = tr + 4 * i;
        dst[(size_t)(dBase + d) * C_ + cBase + tc] = tile[tc][d];
    }
}

// -------------------------------------------------------------------------
// A-RESIDENT single-term bf16 MFMA scoring GEMM:
// r14 accounting: the old structure staged 512 MB/dispatch (A re-fetched
// 4x/block x 2 half-blocks); MFMA (4us) and LDS BW (10us) were nowhere near
// the 94us wall -> traffic/latency-bound. Fix: 64-row blocks covering ALL
// 1024 codes; A (64 rows x 512 k bf16 = 64 KB) staged ONCE into resident
// LDS; only B double-buffers (2 x 16 KB). A-fetch 256 MB -> 32 MB.
// LDS = 96 KB -> 2 blocks/CU. Wave = 64 rows x 32 codes (acc[4][2]);
// quarter = wave-id, st arrays / merge unchanged.
__global__ __launch_bounds__(256, 2)
void rvq_gemm_pipe_kernel(const unsigned short* __restrict__ ahi, // residual hi [ROWS][D_]
                          const unsigned short* __restrict__ cbh, // stage cb hi [C_][D_]
                          const float* __restrict__ norms_s,      // [C_]
                          float* __restrict__ st_m1,              // [4][ROWS]
                          float* __restrict__ st_m2,              // [4][ROWS]
                          int* __restrict__ st_i1)                // [4][ROWS]
{
    __shared__ char lds[98304];        // A resident [16][64][32]bf16 (64KB) + B dbuf (32KB)
    char* const ldsA = lds;            // sub-tile kt32 at ldsA + kt32*4096
    char* const ldsB = lds + 65536;    // ldsB + db*16384 + sub*8192

    const int tid  = threadIdx.x;
    const int lane = tid & 63;
    const int lc   = lane & 15;        // code/row lane within frag
    const int lq   = lane >> 4;        // k-chunk of fragment
    const int wv   = tid >> 6;         // wave = 32-code slice (0..3) = quarter
    const int rowBase = blockIdx.x * 64;

    const int srow = lane >> 2;                      // 0..15 (row within 1KB issue)
    const int qsw  = (lane & 3) ^ ((srow >> 1) & 3); // inverse-swizzled k-slot

    // ---- prologue: stage resident A (64 rows x 512 k), 16 issues/wave
    #pragma unroll
    for (int i = 0; i < 16; ++i) {
        const int s    = wv * 16 + i;   // 0..63
        const int kt32 = s >> 2;        // 32-k sub-tile (0..15)
        const int j    = s & 3;         // 16-row group
        gload16(ahi + (size_t)(rowBase + j * 16 + srow) * D_ + kt32 * 32 + qsw * 8,
                ldsA + kt32 * 4096 + j * 1024);
    }

    // ---- B staging: one 64-k tile (128 codes) = 16 KB = 4 issues/wave
    auto STAGE_B = [&](int db, int c, int kt) {
        #pragma unroll
        for (int i = 0; i < 4; ++i) {
            const int s   = wv * 4 + i; // 0..15
            const int sub = s >> 3;     // 32-k half
            const int j   = s & 7;      // 16-code group
            gload16(cbh + (size_t)(c * 128 + j * 16 + srow) * D_ + kt * 64 + sub * 32 + qsw * 8,
                    ldsB + db * 16384 + sub * 8192 + j * 1024);
        }
    };

    float c_m1 = INFINITY, c_m2 = INFINITY;
    int   c_i1 = 0;

    STAGE_B(0, 0, 0);
    __syncthreads();   // A + B tile 0 landed

    for (int chunk = 0; chunk < 8; ++chunk) {      // 8 x 128-code chunks
        f32x4 acc[4][2];
        #pragma unroll
        for (int m = 0; m < 4; ++m)
            #pragma unroll
            for (int n = 0; n < 2; ++n) acc[m][n] = (f32x4){0.f, 0.f, 0.f, 0.f};

        for (int kt = 0; kt < 8; ++kt) {           // 8 x 64-k tiles
            const int t  = chunk * 8 + kt;
            const int db = t & 1;
            if (t + 1 < 64)
                STAGE_B(db ^ 1, (t + 1) >> 3, (t + 1) & 7);

            #pragma unroll
            for (int sub = 0; sub < 2; ++sub) {
                char* AhiB = ldsA + (kt * 2 + sub) * 4096;
                char* BhiB = ldsB + db * 16384 + sub * 8192;

                bf16x8 ah[4], bh[2];
                #pragma unroll
                for (int m = 0; m < 4; ++m)
                    ah[m] = *(const bf16x8*)(AhiB + swzoff(m * 16 + lc, lq));
                #pragma unroll
                for (int n = 0; n < 2; ++n)
                    bh[n] = *(const bf16x8*)(BhiB + swzoff(wv * 32 + n * 16 + lc, lq));
                #pragma unroll
                for (int m = 0; m < 4; ++m)
                    #pragma unroll
                    for (int n = 0; n < 2; ++n)
                        acc[m][n] = MF(ah[m], bh[n], acc[m][n]);
            }
            // ONE barrier per 64-k step: B ds_reads done, next-B prefetch
            // committed (compiler drains vmcnt+lgkm). A is read-only resident.
            __syncthreads();
        }

        // ---- fold chunk scores into carried top-2 (regs + shfl only)
        const int cbase = chunk * 128 + wv * 32;
        const float nrm0 = norms_s[cbase + lc];
        const float nrm1 = norms_s[cbase + 16 + lc];
        #pragma unroll
        for (int m = 0; m < 4; ++m) {
            #pragma unroll
            for (int r = 0; r < 4; ++r) {
                float s0 = fmaf(-2.f, acc[m][0][r], nrm0);
                float s1 = fmaf(-2.f, acc[m][1][r], nrm1);
                float m1 = s0, m2 = INFINITY;
                int   i1 = cbase + lc;
                if (s1 < m1) { m2 = m1; m1 = s1; i1 = cbase + 16 + lc; } else m2 = fminf(m2, s1);
                #pragma unroll
                for (int d = 1; d < 16; d <<= 1) {
                    float om1 = __shfl_xor(m1, d);
                    int   oi1 = __shfl_xor(i1, d);
                    float om2 = __shfl_xor(m2, d);
                    bool take = (om1 < m1) || (om1 == m1 && oi1 < i1);
                    float lose1 = take ? m1 : om1;
                    m2 = fminf(fminf(m2, om2), lose1);
                    m1 = take ? om1 : m1;
                    i1 = take ? oi1 : i1;
                }
                if (lc == (m * 4 + r)) {
                    bool take = (m1 < c_m1) || (m1 == c_m1 && i1 < c_i1);
                    float lose1 = take ? c_m1 : m1;
                    c_m2 = fminf(fminf(c_m2, m2), lose1);
                    c_m1 = take ? m1 : c_m1;
                    c_i1 = take ? i1 : c_i1;
                }
            }
        }
    }

    const int myrow = rowBase + (lc >> 2) * 16 + lq * 4 + (lc & 3);
    const int quarter = wv;
    st_m1[quarter * ROWS + myrow] = c_m1;
    st_m2[quarter * ROWS + myrow] = c_m2;
    st_i1[quarter * ROWS + myrow] = c_i1;
}

// -------------------------------------------------------------------------
// Fallback GEMM (single-term, reg-staged, in-loop A conversion) — used only
// if ws_size is too small for preconverted residuals.
__global__ __launch_bounds__(256, 2)
void rvq_gemm_fallback_kernel(const float* __restrict__ src,
                              const unsigned short* __restrict__ cbh,
                              const float* __restrict__ norms_s,
                              float* __restrict__ st_m1,
                              float* __restrict__ st_m2,
                              int* __restrict__ st_i1)
{
    __shared__ char lds[16384];
    char* AhiB = lds;
    char* BhiB = lds + 8192;

    const int tid  = threadIdx.x;
    const int lane = tid & 63;
    const int lc   = lane & 15;
    const int lq   = lane >> 4;
    const int wv   = tid >> 6;
    const int wr   = wv >> 1;
    const int wc   = wv & 1;
    const int rowBase = blockIdx.x * 128;
    const int half = blockIdx.y;

    float c_m1 = INFINITY, c_m2 = INFINITY;
    int   c_i1 = 0;

    const int arow  = tid >> 1;
    const int ahalf = tid & 1;

    for (int chunk = 0; chunk < 4; ++chunk) {
        const int codeBase = half * 512 + chunk * 128;
        f32x4 acc[4][4];
        #pragma unroll
        for (int m = 0; m < 4; ++m)
            #pragma unroll
            for (int n = 0; n < 4; ++n) acc[m][n] = (f32x4){0.f, 0.f, 0.f, 0.f};

        for (int kt = 0; kt < D_ / 32; ++kt) {
            __syncthreads();
            {
                const float* ap = src + (size_t)(rowBase + arow) * D_ + kt * 32 + ahalf * 16;
                float fv[16];
                *(float4*)&fv[0]  = ((const float4*)ap)[0];
                *(float4*)&fv[4]  = ((const float4*)ap)[1];
                *(float4*)&fv[8]  = ((const float4*)ap)[2];
                *(float4*)&fv[12] = ((const float4*)ap)[3];
                bf16x8 H0, H1;
                #pragma unroll
                for (int j = 0; j < 8; ++j) {
                    H0[j] = (short)bf16rn(fv[j]);
                    H1[j] = (short)bf16rn(fv[j + 8]);
                }
                const int q0 = ahalf * 2;
                *(bf16x8*)(AhiB + swzoff(arow, q0))     = H0;
                *(bf16x8*)(AhiB + swzoff(arow, q0 + 1)) = H1;
            }
            {
                const size_t boff = (size_t)(codeBase + arow) * D_ + kt * 32 + ahalf * 16;
                bf16x8 bh0 = *(const bf16x8*)(cbh + boff);
                bf16x8 bh1 = *(const bf16x8*)(cbh + boff + 8);
                const int q0 = ahalf * 2;
                *(bf16x8*)(BhiB + swzoff(arow, q0))     = bh0;
                *(bf16x8*)(BhiB + swzoff(arow, q0 + 1)) = bh1;
            }
            __syncthreads();
            bf16x8 ah[4], bh[4];
            #pragma unroll
            for (int m = 0; m < 4; ++m)
                ah[m] = *(const bf16x8*)(AhiB + swzoff(wr * 64 + m * 16 + lc, lq));
            #pragma unroll
            for (int n = 0; n < 4; ++n)
                bh[n] = *(const bf16x8*)(BhiB + swzoff(wc * 64 + n * 16 + lc, lq));
            #pragma unroll
            for (int m = 0; m < 4; ++m)
                #pragma unroll
                for (int n = 0; n < 4; ++n)
                    acc[m][n] = MF(ah[m], bh[n], acc[m][n]);
        }

        const int cbase = codeBase + wc * 64;
        const float nrm0 = norms_s[cbase + lc];
        const float nrm1 = norms_s[cbase + 16 + lc];
        const float nrm2 = norms_s[cbase + 32 + lc];
        const float nrm3 = norms_s[cbase + 48 + lc];
        #pragma unroll
        for (int m = 0; m < 4; ++m) {
            #pragma unroll
            for (int r = 0; r < 4; ++r) {
                float s0 = fmaf(-2.f, acc[m][0][r], nrm0);
                float s1 = fmaf(-2.f, acc[m][1][r], nrm1);
                float s2 = fmaf(-2.f, acc[m][2][r], nrm2);
                float s3 = fmaf(-2.f, acc[m][3][r], nrm3);
                float m1 = s0, m2 = INFINITY;
                int   i1 = cbase + lc;
                if (s1 < m1) { m2 = m1; m1 = s1; i1 = cbase + 16 + lc; } else m2 = fminf(m2, s1);
                if (s2 < m1) { m2 = m1; m1 = s2; i1 = cbase + 32 + lc; } else m2 = fminf(m2, s2);
                if (s3 < m1) { m2 = m1; m1 = s3; i1 = cbase + 48 + lc; } else m2 = fminf(m2, s3);
                #pragma unroll
                for (int d = 1; d < 16; d <<= 1) {
                    float om1 = __shfl_xor(m1, d);
                    int   oi1 = __shfl_xor(i1, d);
                    float om2 = __shfl_xor(m2, d);
                    bool take = (om1 < m1) || (om1 == m1 && oi1 < i1);
                    float lose1 = take ? m1 : om1;
                    m2 = fminf(fminf(m2, om2), lose1);
                    m1 = take ? om1 : m1;
                    i1 = take ? oi1 : i1;
                }
                if (lc == (m * 4 + r)) {
                    bool take = (m1 < c_m1) || (m1 == c_m1 && i1 < c_i1);
                    float lose1 = take ? c_m1 : m1;
                    c_m2 = fminf(fminf(c_m2, m2), lose1);
                    c_m1 = take ? m1 : c_m1;
                    c_i1 = take ? i1 : c_i1;
                }
            }
        }
    }

    const int myrow = rowBase + wr * 64 + (lc >> 2) * 16 + lq * 4 + (lc & 3);
    const int quarter = half * 2 + wc;
    st_m1[quarter * ROWS + myrow] = c_m1;
    st_m2[quarter * ROWS + myrow] = c_m2;
    st_i1[quarter * ROWS + myrow] = c_i1;
}

// -------------------------------------------------------------------------
// merge 4 quarters -> final idx; near-tie rows appended to compact rescue list
__global__ __launch_bounds__(256)
void merge_kernel(const float* __restrict__ st_m1, const float* __restrict__ st_m2,
                  const int* __restrict__ st_i1,
                  int* __restrict__ idx_i, float* __restrict__ idx_f,
                  int* __restrict__ list, int* __restrict__ nflag, int q) {
    const int row = blockIdx.x * 256 + threadIdx.x;
    float m1 = st_m1[row], m2 = st_m2[row];
    int   i1 = st_i1[row];
    #pragma unroll
    for (int qt = 1; qt < 4; ++qt) {
        float om1 = st_m1[qt * ROWS + row];
        float om2 = st_m2[qt * ROWS + row];
        int   oi1 = st_i1[qt * ROWS + row];
        if (om1 < m1) { m2 = fminf(m1, om2); m1 = om1; i1 = oi1; }
        else          { m2 = fminf(m2, om1); }
    }
    idx_i[row] = i1;
    idx_f[(size_t)row * Q_ + q] = (float)i1;
    if (m2 - m1 < TAU) {
        const int p = atomicAdd(nflag, 1);
        list[p] = row;
    }
}

// -------------------------------------------------------------------------
// Parallel exact-f32 rescue, coalesced via transposed codebook cbT[k][c].
__global__ __launch_bounds__(256)
void rescue_par_kernel(const float* __restrict__ src, const float* __restrict__ cbT_s,
                       const float* __restrict__ norms_s,
                       const int* __restrict__ list, const int* __restrict__ nflag_p,
                       unsigned long long* __restrict__ pk)
{
    __shared__ float As[D_][RCH];      // flagged rows, [k][row] (16 KB)
    __shared__ int   rows_s[RCH];
    const int nflag = nflag_p[0];
    const int nitems = ((nflag + RCH - 1) / RCH) * 4;
    const int tid  = threadIdx.x;
    const int lane = tid & 63;

    for (int item = blockIdx.x; item < nitems; item += gridDim.x) {
        const int chunk   = item >> 2;
        const int quarter = item & 3;
        __syncthreads();   // previous item's readers done before overwrite
        if (tid < RCH) {
            const int li = chunk * RCH + tid;
            rows_s[tid] = list[li < nflag ? li : nflag - 1];   // pad = dup last
        }
        __syncthreads();
        #pragma unroll
        for (int i = 0; i < 4; ++i) {
            const int v  = tid + 256 * i;
            const int r  = v >> 7;
            const int k4 = (v & 127) * 4;
            float4 f = *(const float4*)(src + (size_t)rows_s[r] * D_ + k4);
            As[k4 + 0][r] = f.x; As[k4 + 1][r] = f.y;
            As[k4 + 2][r] = f.z; As[k4 + 3][r] = f.w;
        }
        __syncthreads();

        const int code = quarter * 256 + tid;
        const float* ct = cbT_s + code;          // element k at ct[k*C_]
        float acc[RCH];
        #pragma unroll
        for (int r = 0; r < RCH; ++r) acc[r] = 0.f;

        float pa[8], pb[8];
        #pragma unroll
        for (int e = 0; e < 8; ++e) pa[e] = ct[(size_t)e * C_];
        for (int k = 0; k < D_; k += 16) {
            #pragma unroll
            for (int e = 0; e < 8; ++e) pb[e] = ct[(size_t)(k + 8 + e) * C_];
            #pragma unroll
            for (int e = 0; e < 8; ++e)
                #pragma unroll
                for (int r = 0; r < RCH; ++r)
                    acc[r] = fmaf(pa[e], As[k + e][r], acc[r]);
            if (k + 16 < D_) {
                #pragma unroll
                for (int e = 0; e < 8; ++e) pa[e] = ct[(size_t)(k + 16 + e) * C_];
            }
            #pragma unroll
            for (int e = 0; e < 8; ++e)
                #pragma unroll
                for (int r = 0; r < RCH; ++r)
                    acc[r] = fmaf(pb[e], As[k + 8 + e][r], acc[r]);
        }

        const float nr = norms_s[code];
        #pragma unroll
        for (int r = 0; r < RCH; ++r) {
            const float s = fmaf(-2.f, acc[r], nr);
            unsigned int u = __builtin_bit_cast(unsigned int, s);
            unsigned int ord = (u & 0x80000000u) ? ~u : (u | 0x80000000u);
            unsigned long long p =
                ((unsigned long long)ord << 32) | (unsigned int)code;
            #pragma unroll
            for (int d = 1; d < 64; d <<= 1) {
                unsigned long long o = __shfl_xor(p, d);
                p = (o < p) ? o : p;
            }
            if (lane == 0) {
                const int li = chunk * RCH + r;
                if (li < nflag)
                    atomicMin(&pk[rows_s[r]], p);
            }
        }
    }
}

// unpack packed winners -> idx_i / idx_f (flagged rows only)
__global__ __launch_bounds__(256)
void rescue_unpack_kernel(const unsigned long long* __restrict__ pk,
                          const int* __restrict__ list,
                          const int* __restrict__ nflag_p,
                          int* __restrict__ idx_i, float* __restrict__ idx_f, int q)
{
    const int nflag = nflag_p[0];
    for (int i = blockIdx.x * 256 + threadIdx.x; i < nflag; i += gridDim.x * 256) {
        const int row  = list[i];
        const int code = (int)(pk[row] & 0xFFFFFFFFull);
        idx_i[row] = code;
        idx_f[(size_t)row * Q_ + q] = (float)code;
    }
}

// -------------------------------------------------------------------------
// Old serial rescue — kept for the no-preconv fallback path only.
#define FMA_HALF(v0, v1, v2, v3, kk)                                  \
    {                                                                 \
        _Pragma("unroll")                                             \
        for (int e = 0; e < 4; ++e) {                                 \
            const float b0e = ((const float*)&(v0))[e];               \
            const float b1e = ((const float*)&(v1))[e];               \
            const float b2e = ((const float*)&(v2))[e];               \
            const float b3e = ((const float*)&(v3))[e];               \
            _Pragma("unroll")                                         \
            for (int r = 0; r < RCH; ++r) {                           \
                const float a = As[(kk) + e][r];                      \
                acc[0][r] = fmaf(b0e, a, acc[0][r]);                  \
                acc[1][r] = fmaf(b1e, a, acc[1][r]);                  \
                acc[2][r] = fmaf(b2e, a, acc[2][r]);                  \
                acc[3][r] = fmaf(b3e, a, acc[3][r]);                  \
            }                                                         \
        }                                                             \
    }

__global__ __launch_bounds__(256)
void rescue_kernel(const float* __restrict__ src, const float* __restrict__ cb,
                   const float* __restrict__ norms_s,
                   const int* __restrict__ list, const int* __restrict__ nflag_p,
                   int* __restrict__ idx_i, float* __restrict__ idx_f, int q)
{
    __shared__ float As[D_][RCH];
    __shared__ int   rows_s[RCH];
    __shared__ float wm[4][RCH];
    __shared__ int   wi[4][RCH];
    const int nflag = nflag_p[0];
    const int tid = threadIdx.x;

    const float* const c0 = cb + (size_t)(tid      ) * D_;
    const float* const c1 = cb + (size_t)(tid + 256) * D_;
    const float* const c2 = cb + (size_t)(tid + 512) * D_;
    const float* const c3 = cb + (size_t)(tid + 768) * D_;

    for (int chunk = blockIdx.x; chunk * RCH < nflag; chunk += gridDim.x) {
        __syncthreads();
        if (tid < RCH) {
            const int li = chunk * RCH + tid;
            rows_s[tid] = list[li < nflag ? li : nflag - 1];
        }
        __syncthreads();
        #pragma unroll
        for (int i = 0; i < 4; ++i) {
            const int v  = tid + 256 * i;
            const int r  = v >> 7;
            const int k4 = (v & 127) * 4;
            float4 f = *(const float4*)(src + (size_t)rows_s[r] * D_ + k4);
            As[k4 + 0][r] = f.x; As[k4 + 1][r] = f.y;
            As[k4 + 2][r] = f.z; As[k4 + 3][r] = f.w;
        }
        __syncthreads();

        float acc[4][RCH];
        #pragma unroll
        for (int j = 0; j < 4; ++j)
            #pragma unroll
            for (int r = 0; r < RCH; ++r) acc[j][r] = 0.f;

        float4 pa0 = *(const float4*)(c0);
        float4 pa1 = *(const float4*)(c1);
        float4 pa2 = *(const float4*)(c2);
        float4 pa3 = *(const float4*)(c3);
        for (int k = 0; k < D_; k += 8) {
            float4 pb0 = *(const float4*)(c0 + k + 4);
            float4 pb1 = *(const float4*)(c1 + k + 4);
            float4 pb2 = *(const float4*)(c2 + k + 4);
            float4 pb3 = *(const float4*)(c3 + k + 4);
            FMA_HALF(pa0, pa1, pa2, pa3, k);
            if (k + 8 < D_) {
                pa0 = *(const float4*)(c0 + k + 8);
                pa1 = *(const float4*)(c1 + k + 8);
                pa2 = *(const float4*)(c2 + k + 8);
                pa3 = *(const float4*)(c3 + k + 8);
            }
            FMA_HALF(pb0, pb1, pb2, pb3, k + 4);
        }

        float m1[RCH]; int i1[RCH];
        #pragma unroll
        for (int r = 0; r < RCH; ++r) { m1[r] = INFINITY; i1[r] = 0; }
        #pragma unroll
        for (int j = 0; j < 4; ++j) {
            const int c = tid + 256 * j;
            const float nr = norms_s[c];
            #pragma unroll
            for (int r = 0; r < RCH; ++r) {
                const float s = fmaf(-2.f, acc[j][r], nr);
                if (s < m1[r]) { m1[r] = s; i1[r] = c; }
            }
        }
        #pragma unroll
        for (int d = 1; d < 64; d <<= 1)
            #pragma unroll
            for (int r = 0; r < RCH; ++r) {
                const float om = __shfl_xor(m1[r], d);
                const int   oi = __shfl_xor(i1[r], d);
                if (om < m1[r] || (om == m1[r] && oi < i1[r])) { m1[r] = om; i1[r] = oi; }
            }
        if ((tid & 63) == 0)
            #pragma unroll
            for (int r = 0; r < RCH; ++r) { wm[tid >> 6][r] = m1[r]; wi[tid >> 6][r] = i1[r]; }
        __syncthreads();
        if (tid < RCH) {
            float bm = wm[0][tid]; int bi = wi[0][tid];
            #pragma unroll
            for (int w = 1; w < 4; ++w)
                if (wm[w][tid] < bm || (wm[w][tid] == bm && wi[w][tid] < bi)) {
                    bm = wm[w][tid]; bi = wi[w][tid];
                }
            const int li = chunk * RCH + tid;
            if (li < nflag) {
                const int row = rows_s[tid];
                idx_i[row] = bi;
                idx_f[(size_t)row * Q_ + q] = (float)bi;
            }
        }
    }
}

// -------------------------------------------------------------------------
// residual update: newres = res - cb[idx] (exact f32); loss; final qout.
__global__ __launch_bounds__(256)
void update_kernel(const float* __restrict__ src, float* __restrict__ dst,
                   const float* __restrict__ x, const float* __restrict__ cb,
                   const int* __restrict__ idx_i, float* __restrict__ loss_out,
                   unsigned short* __restrict__ rhi,
                   int is_last, int write_hl) {
    __shared__ int ids[64];
    const int tid = threadIdx.x;
    const int rowBase = blockIdx.x * 64;
    if (tid < 64) ids[tid] = idx_i[rowBase + tid];
    __syncthreads();
    float lsum = 0.f;
    #pragma unroll 4
    for (int e4 = tid; e4 < 64 * D_ / 4; e4 += 256) {
        const int row  = e4 >> 7;
        const int d    = (e4 & 127) * 4;
        const int code = ids[row];
        const size_t off = (size_t)(rowBase + row) * D_ + d;
        float4 r = *(const float4*)(src + off);
        float4 e = *(const float4*)(cb + (size_t)code * D_ + d);
        float4 nr = make_float4(r.x - e.x, r.y - e.y, r.z - e.z, r.w - e.w);
        lsum += nr.x * nr.x + nr.y * nr.y + nr.z * nr.z + nr.w * nr.w;
        if (is_last) {
            float4 xv = *(const float4*)(x + off);
            *(float4*)(dst + off) = make_float4(xv.x - nr.x, xv.y - nr.y,
                                                xv.z - nr.z, xv.w - nr.w);
        } else {
            *(float4*)(dst + off) = nr;
        }
        if (write_hl) {
            ushort4 h;
            h.x = bf16rn(nr.x);
            h.y = bf16rn(nr.y);
            h.z = bf16rn(nr.z);
            h.w = bf16rn(nr.w);
            *(ushort4*)(rhi + off) = h;
        }
    }
    #pragma unroll
    for (int m = 1; m < 64; m <<= 1) lsum += __shfl_xor(lsum, m);
    if ((tid & 63) == 0)
        atomicAdd(loss_out, lsum * (1.0f / ((float)ROWS * (float)D_)));
}

// -------------------------------------------------------------------------
extern "C" void kernel_launch(void* const* d_in, const int* in_sizes, int n_in,
                              void* d_out, int out_size, void* d_ws, size_t ws_size,
                              hipStream_t stream) {
    const float* x  = (const float*)d_in[0];   // [B,N,D]
    const float* cb = (const float*)d_in[1];   // [Q,C,D]

    float* qout   = (float*)d_out;                                  // doubles as residual
    float* idx_f  = (float*)d_out + (size_t)ROWS * D_;              // [ROWS][Q_] as floats
    float* losses = idx_f + (size_t)ROWS * Q_;                      // [Q_]

    char* w = (char*)d_ws;
    unsigned short* cb_hi = (unsigned short*)w;                     // Q*C*D bf16 (8MB)
    float* cbT = (float*)(cb_hi + (size_t)Q_ * C_ * D_);            // Q*D*C f32 (16MB)
    float* norms = cbT + (size_t)Q_ * C_ * D_;                      // Q*C
    float* st_m1 = norms + Q_ * C_;                                 // 4*ROWS
    float* st_m2 = st_m1 + 4 * ROWS;
    int*   st_i1 = (int*)(st_m2 + 4 * ROWS);
    int*   idx_i = st_i1 + 4 * ROWS;                                // ROWS
    int*   list  = idx_i + ROWS;                                    // ROWS
    int*   nflag = list + ROWS;                                     // 8 counters + pad
    unsigned long long* pk = (unsigned long long*)(nflag + 64);     // ROWS u64 (256KB)
    unsigned short* res_hi = (unsigned short*)(pk + ROWS);          // ROWS*D (32MB)

    const size_t need = (size_t)((char*)(res_hi + (size_t)ROWS * D_) - w);
    const int preconv = (ws_size >= need) ? 1 : 0;

    hipMemsetAsync(losses, 0, Q_ * sizeof(float), stream);
    hipMemsetAsync(nflag, 0, 8 * sizeof(int), stream);   // all stages' counters
    conv_hi_kernel<<<Q_ * C_ * D_ / 1024, 256, 0, stream>>>(cb, cb_hi);
    code_norms_kernel<<<Q_ * C_ / 4, 256, 0, stream>>>(cb, norms);
    if (preconv) {
        conv_hi_kernel<<<(int)((size_t)ROWS * D_ / 1024), 256, 0, stream>>>(x, res_hi);
        cb_transpose_kernel<<<dim3(D_ / 64, C_ / 64, Q_), 256, 0, stream>>>(cb, cbT);
    }

    for (int q = 0; q < Q_; ++q) {
        const float* src = (q == 0) ? x : qout;
        const float* cb_s = cb + (size_t)q * C_ * D_;
        if (preconv)
            rvq_gemm_pipe_kernel<<<ROWS / 64, 256, 0, stream>>>(
                res_hi, cb_hi + (size_t)q * C_ * D_,
                norms + (size_t)q * C_, st_m1, st_m2, st_i1);
        else
            rvq_gemm_fallback_kernel<<<dim3(ROWS / 128, 2), 256, 0, stream>>>(
                src, cb_hi + (size_t)q * C_ * D_,
                norms + (size_t)q * C_, st_m1, st_m2, st_i1);
        merge_kernel<<<ROWS / 256, 256, 0, stream>>>(
            st_m1, st_m2, st_i1, idx_i, idx_f, list, nflag + q, q);
        if (preconv) {
            hipMemsetAsync(pk, 0xFF, (size_t)ROWS * sizeof(unsigned long long), stream);
            rescue_par_kernel<<<1024, 256, 0, stream>>>(
                src, cbT + (size_t)q * D_ * C_, norms + (size_t)q * C_,
                list, nflag + q, pk);
            rescue_unpack_kernel<<<64, 256, 0, stream>>>(
                pk, list, nflag + q, idx_i, idx_f, q);
        } else {
            rescue_kernel<<<256, 256, 0, stream>>>(
                src, cb_s, norms + (size_t)q * C_, list, nflag + q, idx_i, idx_f, q);
        }
        update_kernel<<<ROWS / 64, 256, 0, stream>>>(
            src, qout, x, cb_s, idx_i, losses + q, res_hi,
            (q == Q_ - 1) ? 1 : 0, (preconv && q < Q_ - 1) ? 1 : 0);
    }
}

// Round 16
// 1368.675 us; speedup vs baseline: 1.5333x; 1.5333x over previous
//
#include <hip/hip_runtime.h>
#include <math.h>

// Problem constants (ResidualVQ: B=8, N=4096, D=512, C=1024, Q=8)
#define B_   8
#define N_   4096
#define D_   512
#define C_   1024
#define Q_   8
#define ROWS (B_ * N_)   // 32768 token rows

#define TAU  1.0f        // rescue margin; 1-term approx err rms ~0.07-0.1 sigma_r
#define RCH  8           // rows per rescue chunk
#define FLAGBIT 0x10000  // flag in idx_i: row needs pk-resolved code (codes < 1024)

typedef __attribute__((ext_vector_type(8))) short bf16x8;
typedef __attribute__((ext_vector_type(4))) float f32x4;

#define MF(a, b, c) __builtin_amdgcn_mfma_f32_16x16x32_bf16(a, b, c, 0, 0, 0)

// round-to-nearest-even f32 -> bf16 (bits)
__device__ __forceinline__ unsigned short bf16rn(float f) {
    unsigned int u = __builtin_bit_cast(unsigned int, f);
    return (unsigned short)((u + 0x7fffu + ((u >> 16) & 1u)) >> 16);
}
// LDS byte offset for tile [row][32 bf16], XOR-swizzled (<=2-way conflicts)
__device__ __forceinline__ int swzoff(int row, int q) {
    return row * 64 + ((q ^ ((row >> 1) & 3)) << 4);
}
// async global->LDS, 16B per lane. LDS dest wave-uniform+lane*16; global src per-lane.
__device__ __forceinline__ void gload16(const void* g, void* l) {
    __builtin_amdgcn_global_load_lds(
        (const __attribute__((address_space(1))) void*)g,
        (__attribute__((address_space(3))) void*)l, 16, 0, 0);
}

// -------------------------------------------------------------------------
// f32 -> bf16 hi (codebooks once per call; x at stage 0)
__global__ __launch_bounds__(256)
void conv_hi_kernel(const float* __restrict__ src, unsigned short* __restrict__ hi) {
    const int i4 = blockIdx.x * 256 + threadIdx.x;
    float4 v = ((const float4*)src)[i4];
    ushort4 h;
    h.x = bf16rn(v.x); h.y = bf16rn(v.y); h.z = bf16rn(v.z); h.w = bf16rn(v.w);
    ((ushort4*)hi)[i4] = h;
}

// ||e||^2 for every code of every stage (exact f32)
__global__ __launch_bounds__(256)
void code_norms_kernel(const float* __restrict__ cb, float* __restrict__ norms) {
    const int code = blockIdx.x * 4 + (threadIdx.x >> 6);
    const int lane = threadIdx.x & 63;
    const float* p = cb + (size_t)code * D_;
    float s = 0.f;
    #pragma unroll
    for (int d = lane * 4; d < D_; d += 256) {
        float4 v = *(const float4*)(p + d);
        s += v.x * v.x + v.y * v.y + v.z * v.z + v.w * v.w;
    }
    #pragma unroll
    for (int m = 1; m < 64; m <<= 1) s += __shfl_xor(s, m);
    if (lane == 0) norms[code] = s;
}

// codebook [q][c][d] -> cbT [q][d][c]  (once per call; coalesced rescue loads)
__global__ __launch_bounds__(256)
void cb_transpose_kernel(const float* __restrict__ cb, float* __restrict__ cbT) {
    __shared__ float tile[64][65];
    const int q = blockIdx.z;
    const int dBase = blockIdx.x * 64;
    const int cBase = blockIdx.y * 64;
    const int tc = threadIdx.x & 63;
    const int tr = threadIdx.x >> 6;   // 0..3
    const float* src = cb + (size_t)q * C_ * D_;
    float* dst = cbT + (size_t)q * D_ * C_;
    #pragma unroll
    for (int i = 0; i < 16; ++i) {
        const int c = tr + 4 * i;
        tile[c][tc] = src[(size_t)(cBase + c) * D_ + dBase + tc];
    }
    __syncthreads();
    #pragma unroll
    for (int i = 0; i < 16; ++i) {
        const int d = tr + 4 * i;
        dst[(size_t)(dBase + d) * C_ + cBase + tc] = tile[tc][d];
    }
}

// -------------------------------------------------------------------------
// Pipelined single-term bf16 MFMA scoring GEMM, BK=64 (r14, proven 94.7us).
// NOTE r15 lesson: 96KB LDS drops to 1 block/CU (160KB limit) and 64-row
// blocks halve B reuse -> stick with 128x512 tile, 64KB LDS, 2 blocks/CU.
__global__ __launch_bounds__(256, 2)
void rvq_gemm_pipe_kernel(const unsigned short* __restrict__ ahi, // residual hi [ROWS][D_]
                          const unsigned short* __restrict__ cbh, // stage cb hi [C_][D_]
                          const float* __restrict__ norms_s,      // [C_]
                          float* __restrict__ st_m1,              // [4][ROWS]
                          float* __restrict__ st_m2,              // [4][ROWS]
                          int* __restrict__ st_i1)                // [4][ROWS]
{
    __shared__ char lds[65536];        // [db:2][sub:2][A:8KB][B:8KB]

    const int tid  = threadIdx.x;
    const int lane = tid & 63;
    const int lc   = lane & 15;        // code/row lane within frag
    const int lq   = lane >> 4;        // k-chunk of fragment
    const int wv   = tid >> 6;
    const int wr   = wv >> 1;          // wave row-half (0..1)
    const int wc   = wv & 1;           // wave code-half (0..1)
    const int rowBase = blockIdx.x * 128;
    const int half = blockIdx.y;

    const int srow = lane >> 2;                      // 0..15 (row within 1KB issue)
    const int qsw  = (lane & 3) ^ ((srow >> 1) & 3); // inverse-swizzled k-slot

    // staging: 32 slots (sub = s>>4, b = (s>>3)&1, j = s&7); wave wv owns 8.
    const unsigned short* bsrc[8];
    int brow[8], isB[8], lof[8], ksub[8];
    #pragma unroll
    for (int i = 0; i < 8; ++i) {
        const int s   = wv * 8 + i;
        const int sub = s >> 4;
        const int b   = (s >> 3) & 1;
        const int j   = s & 7;
        bsrc[i] = b ? cbh : ahi;
        brow[i] = j * 16 + srow;
        isB[i]  = b;
        ksub[i] = sub * 32;
        lof[i]  = sub * 16384 + b * 8192 + j * 1024;
    }

    auto STAGE = [&](int db, int c, int kt) {   // kt: 64-k tile index (0..7)
        char* lb = lds + db * 32768;
        #pragma unroll
        for (int i = 0; i < 8; ++i) {
            const int grow = (isB[i] ? (half * 512 + c * 128) : rowBase) + brow[i];
            gload16(bsrc[i] + (size_t)grow * D_ + kt * 64 + ksub[i] + qsw * 8,
                    lb + lof[i]);
        }
    };

    float c_m1 = INFINITY, c_m2 = INFINITY;
    int   c_i1 = 0;

    STAGE(0, 0, 0);
    __syncthreads();   // tile 0 landed

    for (int chunk = 0; chunk < 4; ++chunk) {
        const int codeBase = half * 512 + chunk * 128;
        f32x4 acc[4][4];
        #pragma unroll
        for (int m = 0; m < 4; ++m)
            #pragma unroll
            for (int n = 0; n < 4; ++n) acc[m][n] = (f32x4){0.f, 0.f, 0.f, 0.f};

        for (int kt = 0; kt < 8; ++kt) {        // 8 x 64-k tiles per chunk
            const int t  = chunk * 8 + kt;
            const int db = t & 1;
            if (t + 1 < 32)
                STAGE(db ^ 1, (t + 1) >> 3, (t + 1) & 7);

            #pragma unroll
            for (int sub = 0; sub < 2; ++sub) {
                char* base = lds + db * 32768 + sub * 16384;
                char* AhiB = base;
                char* BhiB = base + 8192;

                bf16x8 ah[4], bh[4];
                #pragma unroll
                for (int m = 0; m < 4; ++m) {
                    const int r = wr * 64 + m * 16 + lc;
                    ah[m] = *(const bf16x8*)(AhiB + swzoff(r, lq));
                }
                #pragma unroll
                for (int n = 0; n < 4; ++n) {
                    const int c = wc * 64 + n * 16 + lc;
                    bh[n] = *(const bf16x8*)(BhiB + swzoff(c, lq));
                }
                #pragma unroll
                for (int m = 0; m < 4; ++m)
                    #pragma unroll
                    for (int n = 0; n < 4; ++n)
                        acc[m][n] = MF(ah[m], bh[n], acc[m][n]);
            }
            __syncthreads();
        }

        // ---- fold chunk scores into carried top-2 (regs + shfl only)
        const int cbase = codeBase + wc * 64;
        const float nrm0 = norms_s[cbase + lc];
        const float nrm1 = norms_s[cbase + 16 + lc];
        const float nrm2 = norms_s[cbase + 32 + lc];
        const float nrm3 = norms_s[cbase + 48 + lc];
        #pragma unroll
        for (int m = 0; m < 4; ++m) {
            #pragma unroll
            for (int r = 0; r < 4; ++r) {
                float s0 = fmaf(-2.f, acc[m][0][r], nrm0);
                float s1 = fmaf(-2.f, acc[m][1][r], nrm1);
                float s2 = fmaf(-2.f, acc[m][2][r], nrm2);
                float s3 = fmaf(-2.f, acc[m][3][r], nrm3);
                float m1 = s0, m2 = INFINITY;
                int   i1 = cbase + lc;
                if (s1 < m1) { m2 = m1; m1 = s1; i1 = cbase + 16 + lc; } else m2 = fminf(m2, s1);
                if (s2 < m1) { m2 = m1; m1 = s2; i1 = cbase + 32 + lc; } else m2 = fminf(m2, s2);
                if (s3 < m1) { m2 = m1; m1 = s3; i1 = cbase + 48 + lc; } else m2 = fminf(m2, s3);
                #pragma unroll
                for (int d = 1; d < 16; d <<= 1) {
                    float om1 = __shfl_xor(m1, d);
                    int   oi1 = __shfl_xor(i1, d);
                    float om2 = __shfl_xor(m2, d);
                    bool take = (om1 < m1) || (om1 == m1 && oi1 < i1);
                    float lose1 = take ? m1 : om1;
                    m2 = fminf(fminf(m2, om2), lose1);
                    m1 = take ? om1 : m1;
                    i1 = take ? oi1 : i1;
                }
                if (lc == (m * 4 + r)) {
                    bool take = (m1 < c_m1) || (m1 == c_m1 && i1 < c_i1);
                    float lose1 = take ? c_m1 : m1;
                    c_m2 = fminf(fminf(c_m2, m2), lose1);
                    c_m1 = take ? m1 : c_m1;
                    c_i1 = take ? i1 : c_i1;
                }
            }
        }
    }

    const int myrow = rowBase + wr * 64 + (lc >> 2) * 16 + lq * 4 + (lc & 3);
    const int quarter = half * 2 + wc;
    st_m1[quarter * ROWS + myrow] = c_m1;
    st_m2[quarter * ROWS + myrow] = c_m2;
    st_i1[quarter * ROWS + myrow] = c_i1;
}

// -------------------------------------------------------------------------
// Fallback GEMM (single-term, reg-staged, in-loop A conversion) — used only
// if ws_size is too small for preconverted residuals.
__global__ __launch_bounds__(256, 2)
void rvq_gemm_fallback_kernel(const float* __restrict__ src,
                              const unsigned short* __restrict__ cbh,
                              const float* __restrict__ norms_s,
                              float* __restrict__ st_m1,
                              float* __restrict__ st_m2,
                              int* __restrict__ st_i1)
{
    __shared__ char lds[16384];
    char* AhiB = lds;
    char* BhiB = lds + 8192;

    const int tid  = threadIdx.x;
    const int lane = tid & 63;
    const int lc   = lane & 15;
    const int lq   = lane >> 4;
    const int wv   = tid >> 6;
    const int wr   = wv >> 1;
    const int wc   = wv & 1;
    const int rowBase = blockIdx.x * 128;
    const int half = blockIdx.y;

    float c_m1 = INFINITY, c_m2 = INFINITY;
    int   c_i1 = 0;

    const int arow  = tid >> 1;
    const int ahalf = tid & 1;

    for (int chunk = 0; chunk < 4; ++chunk) {
        const int codeBase = half * 512 + chunk * 128;
        f32x4 acc[4][4];
        #pragma unroll
        for (int m = 0; m < 4; ++m)
            #pragma unroll
            for (int n = 0; n < 4; ++n) acc[m][n] = (f32x4){0.f, 0.f, 0.f, 0.f};

        for (int kt = 0; kt < D_ / 32; ++kt) {
            __syncthreads();
            {
                const float* ap = src + (size_t)(rowBase + arow) * D_ + kt * 32 + ahalf * 16;
                float fv[16];
                *(float4*)&fv[0]  = ((const float4*)ap)[0];
                *(float4*)&fv[4]  = ((const float4*)ap)[1];
                *(float4*)&fv[8]  = ((const float4*)ap)[2];
                *(float4*)&fv[12] = ((const float4*)ap)[3];
                bf16x8 H0, H1;
                #pragma unroll
                for (int j = 0; j < 8; ++j) {
                    H0[j] = (short)bf16rn(fv[j]);
                    H1[j] = (short)bf16rn(fv[j + 8]);
                }
                const int q0 = ahalf * 2;
                *(bf16x8*)(AhiB + swzoff(arow, q0))     = H0;
                *(bf16x8*)(AhiB + swzoff(arow, q0 + 1)) = H1;
            }
            {
                const size_t boff = (size_t)(codeBase + arow) * D_ + kt * 32 + ahalf * 16;
                bf16x8 bh0 = *(const bf16x8*)(cbh + boff);
                bf16x8 bh1 = *(const bf16x8*)(cbh + boff + 8);
                const int q0 = ahalf * 2;
                *(bf16x8*)(BhiB + swzoff(arow, q0))     = bh0;
                *(bf16x8*)(BhiB + swzoff(arow, q0 + 1)) = bh1;
            }
            __syncthreads();
            bf16x8 ah[4], bh[4];
            #pragma unroll
            for (int m = 0; m < 4; ++m)
                ah[m] = *(const bf16x8*)(AhiB + swzoff(wr * 64 + m * 16 + lc, lq));
            #pragma unroll
            for (int n = 0; n < 4; ++n)
                bh[n] = *(const bf16x8*)(BhiB + swzoff(wc * 64 + n * 16 + lc, lq));
            #pragma unroll
            for (int m = 0; m < 4; ++m)
                #pragma unroll
                for (int n = 0; n < 4; ++n)
                    acc[m][n] = MF(ah[m], bh[n], acc[m][n]);
        }

        const int cbase = codeBase + wc * 64;
        const float nrm0 = norms_s[cbase + lc];
        const float nrm1 = norms_s[cbase + 16 + lc];
        const float nrm2 = norms_s[cbase + 32 + lc];
        const float nrm3 = norms_s[cbase + 48 + lc];
        #pragma unroll
        for (int m = 0; m < 4; ++m) {
            #pragma unroll
            for (int r = 0; r < 4; ++r) {
                float s0 = fmaf(-2.f, acc[m][0][r], nrm0);
                float s1 = fmaf(-2.f, acc[m][1][r], nrm1);
                float s2 = fmaf(-2.f, acc[m][2][r], nrm2);
                float s3 = fmaf(-2.f, acc[m][3][r], nrm3);
                float m1 = s0, m2 = INFINITY;
                int   i1 = cbase + lc;
                if (s1 < m1) { m2 = m1; m1 = s1; i1 = cbase + 16 + lc; } else m2 = fminf(m2, s1);
                if (s2 < m1) { m2 = m1; m1 = s2; i1 = cbase + 32 + lc; } else m2 = fminf(m2, s2);
                if (s3 < m1) { m2 = m1; m1 = s3; i1 = cbase + 48 + lc; } else m2 = fminf(m2, s3);
                #pragma unroll
                for (int d = 1; d < 16; d <<= 1) {
                    float om1 = __shfl_xor(m1, d);
                    int   oi1 = __shfl_xor(i1, d);
                    float om2 = __shfl_xor(m2, d);
                    bool take = (om1 < m1) || (om1 == m1 && oi1 < i1);
                    float lose1 = take ? m1 : om1;
                    m2 = fminf(fminf(m2, om2), lose1);
                    m1 = take ? om1 : m1;
                    i1 = take ? oi1 : i1;
                }
                if (lc == (m * 4 + r)) {
                    bool take = (m1 < c_m1) || (m1 == c_m1 && i1 < c_i1);
                    float lose1 = take ? c_m1 : m1;
                    c_m2 = fminf(fminf(c_m2, m2), lose1);
                    c_m1 = take ? m1 : c_m1;
                    c_i1 = take ? i1 : c_i1;
                }
            }
        }
    }

    const int myrow = rowBase + wr * 64 + (lc >> 2) * 16 + lq * 4 + (lc & 3);
    const int quarter = half * 2 + wc;
    st_m1[quarter * ROWS + myrow] = c_m1;
    st_m2[quarter * ROWS + myrow] = c_m2;
    st_i1[quarter * ROWS + myrow] = c_i1;
}

// -------------------------------------------------------------------------
// merge 4 quarters -> final idx (FLAGBIT-tagged if near-tie); flagged rows
// appended to compact rescue list AND their pk slot initialized (replaces
// the per-stage 256KB memset).
__global__ __launch_bounds__(256)
void merge_kernel(const float* __restrict__ st_m1, const float* __restrict__ st_m2,
                  const int* __restrict__ st_i1,
                  int* __restrict__ idx_i, float* __restrict__ idx_f,
                  int* __restrict__ list, int* __restrict__ nflag,
                  unsigned long long* __restrict__ pk, int q) {
    const int row = blockIdx.x * 256 + threadIdx.x;
    float m1 = st_m1[row], m2 = st_m2[row];
    int   i1 = st_i1[row];
    #pragma unroll
    for (int qt = 1; qt < 4; ++qt) {
        float om1 = st_m1[qt * ROWS + row];
        float om2 = st_m2[qt * ROWS + row];
        int   oi1 = st_i1[qt * ROWS + row];
        if (om1 < m1) { m2 = fminf(m1, om2); m1 = om1; i1 = oi1; }
        else          { m2 = fminf(m2, om1); }
    }
    idx_f[(size_t)row * Q_ + q] = (float)i1;   // approx winner (flagged rows fixed by update)
    if (m2 - m1 < TAU) {
        idx_i[row] = i1 | FLAGBIT;
        pk[row] = ~0ULL;                        // init for rescue's atomicMin
        const int p = atomicAdd(nflag, 1);
        list[p] = row;
    } else {
        idx_i[row] = i1;
    }
}

// -------------------------------------------------------------------------
// Parallel exact-f32 rescue, coalesced via transposed codebook cbT[k][c].
__global__ __launch_bounds__(256)
void rescue_par_kernel(const float* __restrict__ src, const float* __restrict__ cbT_s,
                       const float* __restrict__ norms_s,
                       const int* __restrict__ list, const int* __restrict__ nflag_p,
                       unsigned long long* __restrict__ pk)
{
    __shared__ float As[D_][RCH];      // flagged rows, [k][row] (16 KB)
    __shared__ int   rows_s[RCH];
    const int nflag = nflag_p[0];
    const int nitems = ((nflag + RCH - 1) / RCH) * 4;
    const int tid  = threadIdx.x;
    const int lane = tid & 63;

    for (int item = blockIdx.x; item < nitems; item += gridDim.x) {
        const int chunk   = item >> 2;
        const int quarter = item & 3;
        __syncthreads();   // previous item's readers done before overwrite
        if (tid < RCH) {
            const int li = chunk * RCH + tid;
            rows_s[tid] = list[li < nflag ? li : nflag - 1];   // pad = dup last
        }
        __syncthreads();
        #pragma unroll
        for (int i = 0; i < 4; ++i) {
            const int v  = tid + 256 * i;
            const int r  = v >> 7;
            const int k4 = (v & 127) * 4;
            float4 f = *(const float4*)(src + (size_t)rows_s[r] * D_ + k4);
            As[k4 + 0][r] = f.x; As[k4 + 1][r] = f.y;
            As[k4 + 2][r] = f.z; As[k4 + 3][r] = f.w;
        }
        __syncthreads();

        const int code = quarter * 256 + tid;
        const float* ct = cbT_s + code;          // element k at ct[k*C_]
        float acc[RCH];
        #pragma unroll
        for (int r = 0; r < RCH; ++r) acc[r] = 0.f;

        float pa[8], pb[8];
        #pragma unroll
        for (int e = 0; e < 8; ++e) pa[e] = ct[(size_t)e * C_];
        for (int k = 0; k < D_; k += 16) {
            #pragma unroll
            for (int e = 0; e < 8; ++e) pb[e] = ct[(size_t)(k + 8 + e) * C_];
            #pragma unroll
            for (int e = 0; e < 8; ++e)
                #pragma unroll
                for (int r = 0; r < RCH; ++r)
                    acc[r] = fmaf(pa[e], As[k + e][r], acc[r]);
            if (k + 16 < D_) {
                #pragma unroll
                for (int e = 0; e < 8; ++e) pa[e] = ct[(size_t)(k + 16 + e) * C_];
            }
            #pragma unroll
            for (int e = 0; e < 8; ++e)
                #pragma unroll
                for (int r = 0; r < RCH; ++r)
                    acc[r] = fmaf(pb[e], As[k + 8 + e][r], acc[r]);
        }

        const float nr = norms_s[code];
        #pragma unroll
        for (int r = 0; r < RCH; ++r) {
            const float s = fmaf(-2.f, acc[r], nr);
            unsigned int u = __builtin_bit_cast(unsigned int, s);
            unsigned int ord = (u & 0x80000000u) ? ~u : (u | 0x80000000u);
            unsigned long long p =
                ((unsigned long long)ord << 32) | (unsigned int)code;
            #pragma unroll
            for (int d = 1; d < 64; d <<= 1) {
                unsigned long long o = __shfl_xor(p, d);
                p = (o < p) ? o : p;
            }
            if (lane == 0) {
                const int li = chunk * RCH + r;
                if (li < nflag)
                    atomicMin(&pk[rows_s[r]], p);
            }
        }
    }
}

// -------------------------------------------------------------------------
// Old serial rescue — kept for the no-preconv fallback path only.
#define FMA_HALF(v0, v1, v2, v3, kk)                                  \
    {                                                                 \
        _Pragma("unroll")                                             \
        for (int e = 0; e < 4; ++e) {                                 \
            const float b0e = ((const float*)&(v0))[e];               \
            const float b1e = ((const float*)&(v1))[e];               \
            const float b2e = ((const float*)&(v2))[e];               \
            const float b3e = ((const float*)&(v3))[e];               \
            _Pragma("unroll")                                         \
            for (int r = 0; r < RCH; ++r) {                           \
                const float a = As[(kk) + e][r];                      \
                acc[0][r] = fmaf(b0e, a, acc[0][r]);                  \
                acc[1][r] = fmaf(b1e, a, acc[1][r]);                  \
                acc[2][r] = fmaf(b2e, a, acc[2][r]);                  \
                acc[3][r] = fmaf(b3e, a, acc[3][r]);                  \
            }                                                         \
        }                                                             \
    }

__global__ __launch_bounds__(256)
void rescue_kernel(const float* __restrict__ src, const float* __restrict__ cb,
                   const float* __restrict__ norms_s,
                   const int* __restrict__ list, const int* __restrict__ nflag_p,
                   int* __restrict__ idx_i, float* __restrict__ idx_f, int q)
{
    __shared__ float As[D_][RCH];
    __shared__ int   rows_s[RCH];
    __shared__ float wm[4][RCH];
    __shared__ int   wi[4][RCH];
    const int nflag = nflag_p[0];
    const int tid = threadIdx.x;

    const float* const c0 = cb + (size_t)(tid      ) * D_;
    const float* const c1 = cb + (size_t)(tid + 256) * D_;
    const float* const c2 = cb + (size_t)(tid + 512) * D_;
    const float* const c3 = cb + (size_t)(tid + 768) * D_;

    for (int chunk = blockIdx.x; chunk * RCH < nflag; chunk += gridDim.x) {
        __syncthreads();
        if (tid < RCH) {
            const int li = chunk * RCH + tid;
            rows_s[tid] = list[li < nflag ? li : nflag - 1];
        }
        __syncthreads();
        #pragma unroll
        for (int i = 0; i < 4; ++i) {
            const int v  = tid + 256 * i;
            const int r  = v >> 7;
            const int k4 = (v & 127) * 4;
            float4 f = *(const float4*)(src + (size_t)rows_s[r] * D_ + k4);
            As[k4 + 0][r] = f.x; As[k4 + 1][r] = f.y;
            As[k4 + 2][r] = f.z; As[k4 + 3][r] = f.w;
        }
        __syncthreads();

        float acc[4][RCH];
        #pragma unroll
        for (int j = 0; j < 4; ++j)
            #pragma unroll
            for (int r = 0; r < RCH; ++r) acc[j][r] = 0.f;

        float4 pa0 = *(const float4*)(c0);
        float4 pa1 = *(const float4*)(c1);
        float4 pa2 = *(const float4*)(c2);
        float4 pa3 = *(const float4*)(c3);
        for (int k = 0; k < D_; k += 8) {
            float4 pb0 = *(const float4*)(c0 + k + 4);
            float4 pb1 = *(const float4*)(c1 + k + 4);
            float4 pb2 = *(const float4*)(c2 + k + 4);
            float4 pb3 = *(const float4*)(c3 + k + 4);
            FMA_HALF(pa0, pa1, pa2, pa3, k);
            if (k + 8 < D_) {
                pa0 = *(const float4*)(c0 + k + 8);
                pa1 = *(const float4*)(c1 + k + 8);
                pa2 = *(const float4*)(c2 + k + 8);
                pa3 = *(const float4*)(c3 + k + 8);
            }
            FMA_HALF(pb0, pb1, pb2, pb3, k + 4);
        }

        float m1[RCH]; int i1[RCH];
        #pragma unroll
        for (int r = 0; r < RCH; ++r) { m1[r] = INFINITY; i1[r] = 0; }
        #pragma unroll
        for (int j = 0; j < 4; ++j) {
            const int c = tid + 256 * j;
            const float nr = norms_s[c];
            #pragma unroll
            for (int r = 0; r < RCH; ++r) {
                const float s = fmaf(-2.f, acc[j][r], nr);
                if (s < m1[r]) { m1[r] = s; i1[r] = c; }
            }
        }
        #pragma unroll
        for (int d = 1; d < 64; d <<= 1)
            #pragma unroll
            for (int r = 0; r < RCH; ++r) {
                const float om = __shfl_xor(m1[r], d);
                const int   oi = __shfl_xor(i1[r], d);
                if (om < m1[r] || (om == m1[r] && oi < i1[r])) { m1[r] = om; i1[r] = oi; }
            }
        if ((tid & 63) == 0)
            #pragma unroll
            for (int r = 0; r < RCH; ++r) { wm[tid >> 6][r] = m1[r]; wi[tid >> 6][r] = i1[r]; }
        __syncthreads();
        if (tid < RCH) {
            float bm = wm[0][tid]; int bi = wi[0][tid];
            #pragma unroll
            for (int w = 1; w < 4; ++w)
                if (wm[w][tid] < bm || (wm[w][tid] == bm && wi[w][tid] < bi)) {
                    bm = wm[w][tid]; bi = wi[w][tid];
                }
            const int li = chunk * RCH + tid;
            if (li < nflag) {
                const int row = rows_s[tid];
                idx_i[row] = bi;
                idx_f[(size_t)row * Q_ + q] = (float)bi;
            }
        }
    }
}

// -------------------------------------------------------------------------
// residual update (fused unpack): resolve FLAGBIT rows from pk (write their
// idx_f), then newres = res - cb[idx] (exact f32); loss; final qout.
__global__ __launch_bounds__(256)
void update_kernel(const float* __restrict__ src, float* __restrict__ dst,
                   const float* __restrict__ x, const float* __restrict__ cb,
                   const int* __restrict__ idx_i,
                   const unsigned long long* __restrict__ pk,
                   float* __restrict__ idx_f, float* __restrict__ loss_out,
                   unsigned short* __restrict__ rhi,
                   int q, int is_last, int write_hl, int use_pk) {
    __shared__ int ids[64];
    const int tid = threadIdx.x;
    const int rowBase = blockIdx.x * 64;
    if (tid < 64) {
        const int row = rowBase + tid;
        int c = idx_i[row];
        if (use_pk && (c & FLAGBIT)) {
            c = (int)(pk[row] & 0xFFFFFFFFull);
            idx_f[(size_t)row * Q_ + q] = (float)c;   // fix approx winner
        }
        ids[tid] = c & 0xFFFF;
    }
    __syncthreads();
    float lsum = 0.f;
    #pragma unroll 4
    for (int e4 = tid; e4 < 64 * D_ / 4; e4 += 256) {
        const int row  = e4 >> 7;
        const int d    = (e4 & 127) * 4;
        const int code = ids[row];
        const size_t off = (size_t)(rowBase + row) * D_ + d;
        float4 r = *(const float4*)(src + off);
        float4 e = *(const float4*)(cb + (size_t)code * D_ + d);
        float4 nr = make_float4(r.x - e.x, r.y - e.y, r.z - e.z, r.w - e.w);
        lsum += nr.x * nr.x + nr.y * nr.y + nr.z * nr.z + nr.w * nr.w;
        if (is_last) {
            float4 xv = *(const float4*)(x + off);
            *(float4*)(dst + off) = make_float4(xv.x - nr.x, xv.y - nr.y,
                                                xv.z - nr.z, xv.w - nr.w);
        } else {
            *(float4*)(dst + off) = nr;
        }
        if (write_hl) {
            ushort4 h;
            h.x = bf16rn(nr.x);
            h.y = bf16rn(nr.y);
            h.z = bf16rn(nr.z);
            h.w = bf16rn(nr.w);
            *(ushort4*)(rhi + off) = h;
        }
    }
    #pragma unroll
    for (int m = 1; m < 64; m <<= 1) lsum += __shfl_xor(lsum, m);
    if ((tid & 63) == 0)
        atomicAdd(loss_out, lsum * (1.0f / ((float)ROWS * (float)D_)));
}

// -------------------------------------------------------------------------
extern "C" void kernel_launch(void* const* d_in, const int* in_sizes, int n_in,
                              void* d_out, int out_size, void* d_ws, size_t ws_size,
                              hipStream_t stream) {
    const float* x  = (const float*)d_in[0];   // [B,N,D]
    const float* cb = (const float*)d_in[1];   // [Q,C,D]

    float* qout   = (float*)d_out;                                  // doubles as residual
    float* idx_f  = (float*)d_out + (size_t)ROWS * D_;              // [ROWS][Q_] as floats
    float* losses = idx_f + (size_t)ROWS * Q_;                      // [Q_]

    char* w = (char*)d_ws;
    unsigned short* cb_hi = (unsigned short*)w;                     // Q*C*D bf16 (8MB)
    float* cbT = (float*)(cb_hi + (size_t)Q_ * C_ * D_);            // Q*D*C f32 (16MB)
    float* norms = cbT + (size_t)Q_ * C_ * D_;                      // Q*C
    float* st_m1 = norms + Q_ * C_;                                 // 4*ROWS
    float* st_m2 = st_m1 + 4 * ROWS;
    int*   st_i1 = (int*)(st_m2 + 4 * ROWS);
    int*   idx_i = st_i1 + 4 * ROWS;                                // ROWS
    int*   list  = idx_i + ROWS;                                    // ROWS
    int*   nflag = list + ROWS;                                     // 8 counters + pad
    unsigned long long* pk = (unsigned long long*)(nflag + 64);     // ROWS u64 (256KB)
    unsigned short* res_hi = (unsigned short*)(pk + ROWS);          // ROWS*D (32MB)

    const size_t need = (size_t)((char*)(res_hi + (size_t)ROWS * D_) - w);
    const int preconv = (ws_size >= need) ? 1 : 0;

    hipMemsetAsync(losses, 0, Q_ * sizeof(float), stream);
    hipMemsetAsync(nflag, 0, 8 * sizeof(int), stream);   // all stages' counters
    conv_hi_kernel<<<Q_ * C_ * D_ / 1024, 256, 0, stream>>>(cb, cb_hi);
    code_norms_kernel<<<Q_ * C_ / 4, 256, 0, stream>>>(cb, norms);
    if (preconv) {
        conv_hi_kernel<<<(int)((size_t)ROWS * D_ / 1024), 256, 0, stream>>>(x, res_hi);
        cb_transpose_kernel<<<dim3(D_ / 64, C_ / 64, Q_), 256, 0, stream>>>(cb, cbT);
    }

    for (int q = 0; q < Q_; ++q) {
        const float* src = (q == 0) ? x : qout;
        const float* cb_s = cb + (size_t)q * C_ * D_;
        if (preconv)
            rvq_gemm_pipe_kernel<<<dim3(ROWS / 128, 2), 256, 0, stream>>>(
                res_hi, cb_hi + (size_t)q * C_ * D_,
                norms + (size_t)q * C_, st_m1, st_m2, st_i1);
        else
            rvq_gemm_fallback_kernel<<<dim3(ROWS / 128, 2), 256, 0, stream>>>(
                src, cb_hi + (size_t)q * C_ * D_,
                norms + (size_t)q * C_, st_m1, st_m2, st_i1);
        merge_kernel<<<ROWS / 256, 256, 0, stream>>>(
            st_m1, st_m2, st_i1, idx_i, idx_f, list, nflag + q, pk, q);
        if (preconv) {
            rescue_par_kernel<<<1024, 256, 0, stream>>>(
                src, cbT + (size_t)q * D_ * C_, norms + (size_t)q * C_,
                list, nflag + q, pk);
        } else {
            rescue_kernel<<<256, 256, 0, stream>>>(
                src, cb_s, norms + (size_t)q * C_, list, nflag + q, idx_i, idx_f, q);
        }
        update_kernel<<<ROWS / 64, 256, 0, stream>>>(
            src, qout, x, cb_s, idx_i, pk, idx_f, losses + q, res_hi,
            q, (q == Q_ - 1) ? 1 : 0, (preconv && q < Q_ - 1) ? 1 : 0, preconv);
    }
}

// Round 17
// 1328.512 us; speedup vs baseline: 1.5796x; 1.0302x over previous
//
#include <hip/hip_runtime.h>
#include <math.h>

// Problem constants (ResidualVQ: B=8, N=4096, D=512, C=1024, Q=8)
#define B_   8
#define N_   4096
#define D_   512
#define C_   1024
#define Q_   8
#define ROWS (B_ * N_)   // 32768 token rows

#define TAU  1.0f        // rescue margin; 1-term approx err rms ~0.07-0.1 sigma_r
#define RCH  8           // rows per rescue chunk
#define FLAGBIT 0x10000  // flag in idx_i: row needs pk-resolved code (codes < 1024)

typedef __attribute__((ext_vector_type(8))) short bf16x8;
typedef __attribute__((ext_vector_type(4))) float f32x4;

#define MF(a, b, c) __builtin_amdgcn_mfma_f32_16x16x32_bf16(a, b, c, 0, 0, 0)

// round-to-nearest-even f32 -> bf16 (bits)
__device__ __forceinline__ unsigned short bf16rn(float f) {
    unsigned int u = __builtin_bit_cast(unsigned int, f);
    return (unsigned short)((u + 0x7fffu + ((u >> 16) & 1u)) >> 16);
}
// LDS byte offset for tile [row][32 bf16], XOR-swizzled (<=2-way conflicts)
__device__ __forceinline__ int swzoff(int row, int q) {
    return row * 64 + ((q ^ ((row >> 1) & 3)) << 4);
}
// async global->LDS, 16B per lane. LDS dest wave-uniform+lane*16; global src per-lane.
__device__ __forceinline__ void gload16(const void* g, void* l) {
    __builtin_amdgcn_global_load_lds(
        (const __attribute__((address_space(1))) void*)g,
        (__attribute__((address_space(3))) void*)l, 16, 0, 0);
}

// -------------------------------------------------------------------------
// f32 -> bf16 hi (codebooks once per call; x at stage 0)
__global__ __launch_bounds__(256)
void conv_hi_kernel(const float* __restrict__ src, unsigned short* __restrict__ hi) {
    const int i4 = blockIdx.x * 256 + threadIdx.x;
    float4 v = ((const float4*)src)[i4];
    ushort4 h;
    h.x = bf16rn(v.x); h.y = bf16rn(v.y); h.z = bf16rn(v.z); h.w = bf16rn(v.w);
    ((ushort4*)hi)[i4] = h;
}

// ||e||^2 for every code of every stage (exact f32)
__global__ __launch_bounds__(256)
void code_norms_kernel(const float* __restrict__ cb, float* __restrict__ norms) {
    const int code = blockIdx.x * 4 + (threadIdx.x >> 6);
    const int lane = threadIdx.x & 63;
    const float* p = cb + (size_t)code * D_;
    float s = 0.f;
    #pragma unroll
    for (int d = lane * 4; d < D_; d += 256) {
        float4 v = *(const float4*)(p + d);
        s += v.x * v.x + v.y * v.y + v.z * v.z + v.w * v.w;
    }
    #pragma unroll
    for (int m = 1; m < 64; m <<= 1) s += __shfl_xor(s, m);
    if (lane == 0) norms[code] = s;
}

// codebook [q][c][d] -> cbT [q][d][c]  (once per call; coalesced rescue loads)
__global__ __launch_bounds__(256)
void cb_transpose_kernel(const float* __restrict__ cb, float* __restrict__ cbT) {
    __shared__ float tile[64][65];
    const int q = blockIdx.z;
    const int dBase = blockIdx.x * 64;
    const int cBase = blockIdx.y * 64;
    const int tc = threadIdx.x & 63;
    const int tr = threadIdx.x >> 6;   // 0..3
    const float* src = cb + (size_t)q * C_ * D_;
    float* dst = cbT + (size_t)q * D_ * C_;
    #pragma unroll
    for (int i = 0; i < 16; ++i) {
        const int c = tr + 4 * i;
        tile[c][tc] = src[(size_t)(cBase + c) * D_ + dBase + tc];
    }
    __syncthreads();
    #pragma unroll
    for (int i = 0; i < 16; ++i) {
        const int d = tr + 4 * i;
        dst[(size_t)(dBase + d) * C_ + cBase + tc] = tile[tc][d];
    }
}

// -------------------------------------------------------------------------
// Pipelined single-term bf16 MFMA scoring GEMM — OCCUPANCY build:
// r16 analysis: per 64-k step ~350-700cy of issue vs ~7100cy measured ->
// ~90% latency stall with only 2 blocks/CU (grid 512, 64KB LDS). Fix: BK=32
// (32KB LDS, r13-proven inner loop) + 4-way code split (grid ROWS/128 x 4,
// 256 codes/block) -> 4 blocks/CU, 16 waves/CU, 2x latency hiding. Staged
// traffic unchanged. st quarter = half*2+wc in 0..7 (st arrays [8][ROWS]).
__global__ __launch_bounds__(256, 4)
void rvq_gemm_pipe_kernel(const unsigned short* __restrict__ ahi, // residual hi [ROWS][D_]
                          const unsigned short* __restrict__ cbh, // stage cb hi [C_][D_]
                          const float* __restrict__ norms_s,      // [C_]
                          float* __restrict__ st_m1,              // [8][ROWS]
                          float* __restrict__ st_m2,              // [8][ROWS]
                          int* __restrict__ st_i1)                // [8][ROWS]
{
    __shared__ char lds[32768];        // [db:2][A:8KB][B:8KB]

    const int tid  = threadIdx.x;
    const int lane = tid & 63;
    const int lc   = lane & 15;        // code/row lane within frag
    const int lq   = lane >> 4;        // k-chunk of fragment
    const int wv   = tid >> 6;
    const int wr   = wv >> 1;          // wave row-half (0..1)
    const int wc   = wv & 1;           // wave code-half (0..1)
    const int rowBase = blockIdx.x * 128;
    const int half = blockIdx.y;       // 256-code group (0..3)

    const int srow = lane >> 2;                      // 0..15 (row within 1KB issue)
    const int qsw  = (lane & 3) ^ ((srow >> 1) & 3); // inverse-swizzled k-slot

    // staging: 16 slots (b = s>>3, j = s&7); wave wv owns 4.
    const unsigned short* bsrc[4];
    int brow[4], isB[4], lof[4];
    #pragma unroll
    for (int i = 0; i < 4; ++i) {
        const int s = wv * 4 + i;
        const int b = s >> 3;          // 0 = A (waves 0,1), 1 = B (waves 2,3)
        const int j = s & 7;
        bsrc[i] = b ? cbh : ahi;
        brow[i] = j * 16 + srow;
        isB[i]  = b;
        lof[i]  = b * 8192 + j * 1024;
    }

    auto STAGE = [&](int db, int c, int kt) {   // kt: 32-k tile index (0..15)
        char* lb = lds + db * 16384;
        #pragma unroll
        for (int i = 0; i < 4; ++i) {
            const int grow = (isB[i] ? (half * 256 + c * 128) : rowBase) + brow[i];
            gload16(bsrc[i] + (size_t)grow * D_ + kt * 32 + qsw * 8, lb + lof[i]);
        }
    };

    float c_m1 = INFINITY, c_m2 = INFINITY;
    int   c_i1 = 0;

    STAGE(0, 0, 0);
    __syncthreads();   // tile 0 landed

    for (int chunk = 0; chunk < 2; ++chunk) {      // 2 x 128-code chunks
        const int codeBase = half * 256 + chunk * 128;
        f32x4 acc[4][4];
        #pragma unroll
        for (int m = 0; m < 4; ++m)
            #pragma unroll
            for (int n = 0; n < 4; ++n) acc[m][n] = (f32x4){0.f, 0.f, 0.f, 0.f};

        for (int kt = 0; kt < 16; ++kt) {
            const int t  = chunk * 16 + kt;
            const int db = t & 1;
            if (t + 1 < 32)
                STAGE(db ^ 1, (t + 1) >> 4, (t + 1) & 15);

            char* base = lds + db * 16384;
            char* AhiB = base;
            char* BhiB = base + 8192;

            bf16x8 ah[4], bh[4];
            #pragma unroll
            for (int m = 0; m < 4; ++m) {
                const int r = wr * 64 + m * 16 + lc;
                ah[m] = *(const bf16x8*)(AhiB + swzoff(r, lq));
            }
            #pragma unroll
            for (int n = 0; n < 4; ++n) {
                const int c = wc * 64 + n * 16 + lc;
                bh[n] = *(const bf16x8*)(BhiB + swzoff(c, lq));
            }
            #pragma unroll
            for (int m = 0; m < 4; ++m)
                #pragma unroll
                for (int n = 0; n < 4; ++n)
                    acc[m][n] = MF(ah[m], bh[n], acc[m][n]);
            __syncthreads();
        }

        // ---- fold chunk scores into carried top-2 (regs + shfl only)
        const int cbase = codeBase + wc * 64;
        const float nrm0 = norms_s[cbase + lc];
        const float nrm1 = norms_s[cbase + 16 + lc];
        const float nrm2 = norms_s[cbase + 32 + lc];
        const float nrm3 = norms_s[cbase + 48 + lc];
        #pragma unroll
        for (int m = 0; m < 4; ++m) {
            #pragma unroll
            for (int r = 0; r < 4; ++r) {
                float s0 = fmaf(-2.f, acc[m][0][r], nrm0);
                float s1 = fmaf(-2.f, acc[m][1][r], nrm1);
                float s2 = fmaf(-2.f, acc[m][2][r], nrm2);
                float s3 = fmaf(-2.f, acc[m][3][r], nrm3);
                float m1 = s0, m2 = INFINITY;
                int   i1 = cbase + lc;
                if (s1 < m1) { m2 = m1; m1 = s1; i1 = cbase + 16 + lc; } else m2 = fminf(m2, s1);
                if (s2 < m1) { m2 = m1; m1 = s2; i1 = cbase + 32 + lc; } else m2 = fminf(m2, s2);
                if (s3 < m1) { m2 = m1; m1 = s3; i1 = cbase + 48 + lc; } else m2 = fminf(m2, s3);
                #pragma unroll
                for (int d = 1; d < 16; d <<= 1) {
                    float om1 = __shfl_xor(m1, d);
                    int   oi1 = __shfl_xor(i1, d);
                    float om2 = __shfl_xor(m2, d);
                    bool take = (om1 < m1) || (om1 == m1 && oi1 < i1);
                    float lose1 = take ? m1 : om1;
                    m2 = fminf(fminf(m2, om2), lose1);
                    m1 = take ? om1 : m1;
                    i1 = take ? oi1 : i1;
                }
                if (lc == (m * 4 + r)) {
                    bool take = (m1 < c_m1) || (m1 == c_m1 && i1 < c_i1);
                    float lose1 = take ? c_m1 : m1;
                    c_m2 = fminf(fminf(c_m2, m2), lose1);
                    c_m1 = take ? m1 : c_m1;
                    c_i1 = take ? i1 : c_i1;
                }
            }
        }
    }

    const int myrow = rowBase + wr * 64 + (lc >> 2) * 16 + lq * 4 + (lc & 3);
    const int quarter = half * 2 + wc;   // 0..7
    st_m1[quarter * ROWS + myrow] = c_m1;
    st_m2[quarter * ROWS + myrow] = c_m2;
    st_i1[quarter * ROWS + myrow] = c_i1;
}

// -------------------------------------------------------------------------
// Fallback GEMM (single-term, reg-staged, in-loop A conversion) — used only
// if ws_size is too small for preconverted residuals. Writes quarters 0..3.
__global__ __launch_bounds__(256, 2)
void rvq_gemm_fallback_kernel(const float* __restrict__ src,
                              const unsigned short* __restrict__ cbh,
                              const float* __restrict__ norms_s,
                              float* __restrict__ st_m1,
                              float* __restrict__ st_m2,
                              int* __restrict__ st_i1)
{
    __shared__ char lds[16384];
    char* AhiB = lds;
    char* BhiB = lds + 8192;

    const int tid  = threadIdx.x;
    const int lane = tid & 63;
    const int lc   = lane & 15;
    const int lq   = lane >> 4;
    const int wv   = tid >> 6;
    const int wr   = wv >> 1;
    const int wc   = wv & 1;
    const int rowBase = blockIdx.x * 128;
    const int half = blockIdx.y;

    float c_m1 = INFINITY, c_m2 = INFINITY;
    int   c_i1 = 0;

    const int arow  = tid >> 1;
    const int ahalf = tid & 1;

    for (int chunk = 0; chunk < 4; ++chunk) {
        const int codeBase = half * 512 + chunk * 128;
        f32x4 acc[4][4];
        #pragma unroll
        for (int m = 0; m < 4; ++m)
            #pragma unroll
            for (int n = 0; n < 4; ++n) acc[m][n] = (f32x4){0.f, 0.f, 0.f, 0.f};

        for (int kt = 0; kt < D_ / 32; ++kt) {
            __syncthreads();
            {
                const float* ap = src + (size_t)(rowBase + arow) * D_ + kt * 32 + ahalf * 16;
                float fv[16];
                *(float4*)&fv[0]  = ((const float4*)ap)[0];
                *(float4*)&fv[4]  = ((const float4*)ap)[1];
                *(float4*)&fv[8]  = ((const float4*)ap)[2];
                *(float4*)&fv[12] = ((const float4*)ap)[3];
                bf16x8 H0, H1;
                #pragma unroll
                for (int j = 0; j < 8; ++j) {
                    H0[j] = (short)bf16rn(fv[j]);
                    H1[j] = (short)bf16rn(fv[j + 8]);
                }
                const int q0 = ahalf * 2;
                *(bf16x8*)(AhiB + swzoff(arow, q0))     = H0;
                *(bf16x8*)(AhiB + swzoff(arow, q0 + 1)) = H1;
            }
            {
                const size_t boff = (size_t)(codeBase + arow) * D_ + kt * 32 + ahalf * 16;
                bf16x8 bh0 = *(const bf16x8*)(cbh + boff);
                bf16x8 bh1 = *(const bf16x8*)(cbh + boff + 8);
                const int q0 = ahalf * 2;
                *(bf16x8*)(BhiB + swzoff(arow, q0))     = bh0;
                *(bf16x8*)(BhiB + swzoff(arow, q0 + 1)) = bh1;
            }
            __syncthreads();
            bf16x8 ah[4], bh[4];
            #pragma unroll
            for (int m = 0; m < 4; ++m)
                ah[m] = *(const bf16x8*)(AhiB + swzoff(wr * 64 + m * 16 + lc, lq));
            #pragma unroll
            for (int n = 0; n < 4; ++n)
                bh[n] = *(const bf16x8*)(BhiB + swzoff(wc * 64 + n * 16 + lc, lq));
            #pragma unroll
            for (int m = 0; m < 4; ++m)
                #pragma unroll
                for (int n = 0; n < 4; ++n)
                    acc[m][n] = MF(ah[m], bh[n], acc[m][n]);
        }

        const int cbase = codeBase + wc * 64;
        const float nrm0 = norms_s[cbase + lc];
        const float nrm1 = norms_s[cbase + 16 + lc];
        const float nrm2 = norms_s[cbase + 32 + lc];
        const float nrm3 = norms_s[cbase + 48 + lc];
        #pragma unroll
        for (int m = 0; m < 4; ++m) {
            #pragma unroll
            for (int r = 0; r < 4; ++r) {
                float s0 = fmaf(-2.f, acc[m][0][r], nrm0);
                float s1 = fmaf(-2.f, acc[m][1][r], nrm1);
                float s2 = fmaf(-2.f, acc[m][2][r], nrm2);
                float s3 = fmaf(-2.f, acc[m][3][r], nrm3);
                float m1 = s0, m2 = INFINITY;
                int   i1 = cbase + lc;
                if (s1 < m1) { m2 = m1; m1 = s1; i1 = cbase + 16 + lc; } else m2 = fminf(m2, s1);
                if (s2 < m1) { m2 = m1; m1 = s2; i1 = cbase + 32 + lc; } else m2 = fminf(m2, s2);
                if (s3 < m1) { m2 = m1; m1 = s3; i1 = cbase + 48 + lc; } else m2 = fminf(m2, s3);
                #pragma unroll
                for (int d = 1; d < 16; d <<= 1) {
                    float om1 = __shfl_xor(m1, d);
                    int   oi1 = __shfl_xor(i1, d);
                    float om2 = __shfl_xor(m2, d);
                    bool take = (om1 < m1) || (om1 == m1 && oi1 < i1);
                    float lose1 = take ? m1 : om1;
                    m2 = fminf(fminf(m2, om2), lose1);
                    m1 = take ? om1 : m1;
                    i1 = take ? oi1 : i1;
                }
                if (lc == (m * 4 + r)) {
                    bool take = (m1 < c_m1) || (m1 == c_m1 && i1 < c_i1);
                    float lose1 = take ? c_m1 : m1;
                    c_m2 = fminf(fminf(c_m2, m2), lose1);
                    c_m1 = take ? m1 : c_m1;
                    c_i1 = take ? i1 : c_i1;
                }
            }
        }
    }

    const int myrow = rowBase + wr * 64 + (lc >> 2) * 16 + lq * 4 + (lc & 3);
    const int quarter = half * 2 + wc;
    st_m1[quarter * ROWS + myrow] = c_m1;
    st_m2[quarter * ROWS + myrow] = c_m2;
    st_i1[quarter * ROWS + myrow] = c_i1;
}

// -------------------------------------------------------------------------
// merge nq quarters -> final idx (FLAGBIT-tagged if near-tie); flagged rows
// appended to compact rescue list AND pk slot initialized.
__global__ __launch_bounds__(256)
void merge_kernel(const float* __restrict__ st_m1, const float* __restrict__ st_m2,
                  const int* __restrict__ st_i1,
                  int* __restrict__ idx_i, float* __restrict__ idx_f,
                  int* __restrict__ list, int* __restrict__ nflag,
                  unsigned long long* __restrict__ pk, int q, int nq) {
    const int row = blockIdx.x * 256 + threadIdx.x;
    float m1 = st_m1[row], m2 = st_m2[row];
    int   i1 = st_i1[row];
    for (int qt = 1; qt < nq; ++qt) {
        float om1 = st_m1[qt * ROWS + row];
        float om2 = st_m2[qt * ROWS + row];
        int   oi1 = st_i1[qt * ROWS + row];
        if (om1 < m1) { m2 = fminf(m1, om2); m1 = om1; i1 = oi1; }
        else          { m2 = fminf(m2, om1); }
    }
    idx_f[(size_t)row * Q_ + q] = (float)i1;   // approx winner (flagged rows fixed by update)
    if (m2 - m1 < TAU) {
        idx_i[row] = i1 | FLAGBIT;
        pk[row] = ~0ULL;                        // init for rescue's atomicMin
        const int p = atomicAdd(nflag, 1);
        list[p] = row;
    } else {
        idx_i[row] = i1;
    }
}

// -------------------------------------------------------------------------
// Parallel exact-f32 rescue, coalesced via transposed codebook cbT[k][c].
__global__ __launch_bounds__(256)
void rescue_par_kernel(const float* __restrict__ src, const float* __restrict__ cbT_s,
                       const float* __restrict__ norms_s,
                       const int* __restrict__ list, const int* __restrict__ nflag_p,
                       unsigned long long* __restrict__ pk)
{
    __shared__ float As[D_][RCH];      // flagged rows, [k][row] (16 KB)
    __shared__ int   rows_s[RCH];
    const int nflag = nflag_p[0];
    const int nitems = ((nflag + RCH - 1) / RCH) * 4;
    const int tid  = threadIdx.x;
    const int lane = tid & 63;

    for (int item = blockIdx.x; item < nitems; item += gridDim.x) {
        const int chunk   = item >> 2;
        const int quarter = item & 3;
        __syncthreads();   // previous item's readers done before overwrite
        if (tid < RCH) {
            const int li = chunk * RCH + tid;
            rows_s[tid] = list[li < nflag ? li : nflag - 1];   // pad = dup last
        }
        __syncthreads();
        #pragma unroll
        for (int i = 0; i < 4; ++i) {
            const int v  = tid + 256 * i;
            const int r  = v >> 7;
            const int k4 = (v & 127) * 4;
            float4 f = *(const float4*)(src + (size_t)rows_s[r] * D_ + k4);
            As[k4 + 0][r] = f.x; As[k4 + 1][r] = f.y;
            As[k4 + 2][r] = f.z; As[k4 + 3][r] = f.w;
        }
        __syncthreads();

        const int code = quarter * 256 + tid;
        const float* ct = cbT_s + code;          // element k at ct[k*C_]
        float acc[RCH];
        #pragma unroll
        for (int r = 0; r < RCH; ++r) acc[r] = 0.f;

        float pa[8], pb[8];
        #pragma unroll
        for (int e = 0; e < 8; ++e) pa[e] = ct[(size_t)e * C_];
        for (int k = 0; k < D_; k += 16) {
            #pragma unroll
            for (int e = 0; e < 8; ++e) pb[e] = ct[(size_t)(k + 8 + e) * C_];
            #pragma unroll
            for (int e = 0; e < 8; ++e)
                #pragma unroll
                for (int r = 0; r < RCH; ++r)
                    acc[r] = fmaf(pa[e], As[k + e][r], acc[r]);
            if (k + 16 < D_) {
                #pragma unroll
                for (int e = 0; e < 8; ++e) pa[e] = ct[(size_t)(k + 16 + e) * C_];
            }
            #pragma unroll
            for (int e = 0; e < 8; ++e)
                #pragma unroll
                for (int r = 0; r < RCH; ++r)
                    acc[r] = fmaf(pb[e], As[k + 8 + e][r], acc[r]);
        }

        const float nr = norms_s[code];
        #pragma unroll
        for (int r = 0; r < RCH; ++r) {
            const float s = fmaf(-2.f, acc[r], nr);
            unsigned int u = __builtin_bit_cast(unsigned int, s);
            unsigned int ord = (u & 0x80000000u) ? ~u : (u | 0x80000000u);
            unsigned long long p =
                ((unsigned long long)ord << 32) | (unsigned int)code;
            #pragma unroll
            for (int d = 1; d < 64; d <<= 1) {
                unsigned long long o = __shfl_xor(p, d);
                p = (o < p) ? o : p;
            }
            if (lane == 0) {
                const int li = chunk * RCH + r;
                if (li < nflag)
                    atomicMin(&pk[rows_s[r]], p);
            }
        }
    }
}

// -------------------------------------------------------------------------
// Old serial rescue — kept for the no-preconv fallback path only.
#define FMA_HALF(v0, v1, v2, v3, kk)                                  \
    {                                                                 \
        _Pragma("unroll")                                             \
        for (int e = 0; e < 4; ++e) {                                 \
            const float b0e = ((const float*)&(v0))[e];               \
            const float b1e = ((const float*)&(v1))[e];               \
            const float b2e = ((const float*)&(v2))[e];               \
            const float b3e = ((const float*)&(v3))[e];               \
            _Pragma("unroll")                                         \
            for (int r = 0; r < RCH; ++r) {                           \
                const float a = As[(kk) + e][r];                      \
                acc[0][r] = fmaf(b0e, a, acc[0][r]);                  \
                acc[1][r] = fmaf(b1e, a, acc[1][r]);                  \
                acc[2][r] = fmaf(b2e, a, acc[2][r]);                  \
                acc[3][r] = fmaf(b3e, a, acc[3][r]);                  \
            }                                                         \
        }                                                             \
    }

__global__ __launch_bounds__(256)
void rescue_kernel(const float* __restrict__ src, const float* __restrict__ cb,
                   const float* __restrict__ norms_s,
                   const int* __restrict__ list, const int* __restrict__ nflag_p,
                   int* __restrict__ idx_i, float* __restrict__ idx_f, int q)
{
    __shared__ float As[D_][RCH];
    __shared__ int   rows_s[RCH];
    __shared__ float wm[4][RCH];
    __shared__ int   wi[4][RCH];
    const int nflag = nflag_p[0];
    const int tid = threadIdx.x;

    const float* const c0 = cb + (size_t)(tid      ) * D_;
    const float* const c1 = cb + (size_t)(tid + 256) * D_;
    const float* const c2 = cb + (size_t)(tid + 512) * D_;
    const float* const c3 = cb + (size_t)(tid + 768) * D_;

    for (int chunk = blockIdx.x; chunk * RCH < nflag; chunk += gridDim.x) {
        __syncthreads();
        if (tid < RCH) {
            const int li = chunk * RCH + tid;
            rows_s[tid] = list[li < nflag ? li : nflag - 1];
        }
        __syncthreads();
        #pragma unroll
        for (int i = 0; i < 4; ++i) {
            const int v  = tid + 256 * i;
            const int r  = v >> 7;
            const int k4 = (v & 127) * 4;
            float4 f = *(const float4*)(src + (size_t)rows_s[r] * D_ + k4);
            As[k4 + 0][r] = f.x; As[k4 + 1][r] = f.y;
            As[k4 + 2][r] = f.z; As[k4 + 3][r] = f.w;
        }
        __syncthreads();

        float acc[4][RCH];
        #pragma unroll
        for (int j = 0; j < 4; ++j)
            #pragma unroll
            for (int r = 0; r < RCH; ++r) acc[j][r] = 0.f;

        float4 pa0 = *(const float4*)(c0);
        float4 pa1 = *(const float4*)(c1);
        float4 pa2 = *(const float4*)(c2);
        float4 pa3 = *(const float4*)(c3);
        for (int k = 0; k < D_; k += 8) {
            float4 pb0 = *(const float4*)(c0 + k + 4);
            float4 pb1 = *(const float4*)(c1 + k + 4);
            float4 pb2 = *(const float4*)(c2 + k + 4);
            float4 pb3 = *(const float4*)(c3 + k + 4);
            FMA_HALF(pa0, pa1, pa2, pa3, k);
            if (k + 8 < D_) {
                pa0 = *(const float4*)(c0 + k + 8);
                pa1 = *(const float4*)(c1 + k + 8);
                pa2 = *(const float4*)(c2 + k + 8);
                pa3 = *(const float4*)(c3 + k + 8);
            }
            FMA_HALF(pb0, pb1, pb2, pb3, k + 4);
        }

        float m1[RCH]; int i1[RCH];
        #pragma unroll
        for (int r = 0; r < RCH; ++r) { m1[r] = INFINITY; i1[r] = 0; }
        #pragma unroll
        for (int j = 0; j < 4; ++j) {
            const int c = tid + 256 * j;
            const float nr = norms_s[c];
            #pragma unroll
            for (int r = 0; r < RCH; ++r) {
                const float s = fmaf(-2.f, acc[j][r], nr);
                if (s < m1[r]) { m1[r] = s; i1[r] = c; }
            }
        }
        #pragma unroll
        for (int d = 1; d < 64; d <<= 1)
            #pragma unroll
            for (int r = 0; r < RCH; ++r) {
                const float om = __shfl_xor(m1[r], d);
                const int   oi = __shfl_xor(i1[r], d);
                if (om < m1[r] || (om == m1[r] && oi < i1[r])) { m1[r] = om; i1[r] = oi; }
            }
        if ((tid & 63) == 0)
            #pragma unroll
            for (int r = 0; r < RCH; ++r) { wm[tid >> 6][r] = m1[r]; wi[tid >> 6][r] = i1[r]; }
        __syncthreads();
        if (tid < RCH) {
            float bm = wm[0][tid]; int bi = wi[0][tid];
            #pragma unroll
            for (int w = 1; w < 4; ++w)
                if (wm[w][tid] < bm || (wm[w][tid] == bm && wi[w][tid] < bi)) {
                    bm = wm[w][tid]; bi = wi[w][tid];
                }
            const int li = chunk * RCH + tid;
            if (li < nflag) {
                const int row = rows_s[tid];
                idx_i[row] = bi;
                idx_f[(size_t)row * Q_ + q] = (float)bi;
            }
        }
    }
}

// -------------------------------------------------------------------------
// residual update (fused unpack): resolve FLAGBIT rows from pk (write their
// idx_f), then newres = res - cb[idx] (exact f32); loss; final qout.
__global__ __launch_bounds__(256)
void update_kernel(const float* __restrict__ src, float* __restrict__ dst,
                   const float* __restrict__ x, const float* __restrict__ cb,
                   const int* __restrict__ idx_i,
                   const unsigned long long* __restrict__ pk,
                   float* __restrict__ idx_f, float* __restrict__ loss_out,
                   unsigned short* __restrict__ rhi,
                   int q, int is_last, int write_hl, int use_pk) {
    __shared__ int ids[64];
    const int tid = threadIdx.x;
    const int rowBase = blockIdx.x * 64;
    if (tid < 64) {
        const int row = rowBase + tid;
        int c = idx_i[row];
        if (use_pk && (c & FLAGBIT)) {
            c = (int)(pk[row] & 0xFFFFFFFFull);
            idx_f[(size_t)row * Q_ + q] = (float)c;   // fix approx winner
        }
        ids[tid] = c & 0xFFFF;
    }
    __syncthreads();
    float lsum = 0.f;
    #pragma unroll 4
    for (int e4 = tid; e4 < 64 * D_ / 4; e4 += 256) {
        const int row  = e4 >> 7;
        const int d    = (e4 & 127) * 4;
        const int code = ids[row];
        const size_t off = (size_t)(rowBase + row) * D_ + d;
        float4 r = *(const float4*)(src + off);
        float4 e = *(const float4*)(cb + (size_t)code * D_ + d);
        float4 nr = make_float4(r.x - e.x, r.y - e.y, r.z - e.z, r.w - e.w);
        lsum += nr.x * nr.x + nr.y * nr.y + nr.z * nr.z + nr.w * nr.w;
        if (is_last) {
            float4 xv = *(const float4*)(x + off);
            *(float4*)(dst + off) = make_float4(xv.x - nr.x, xv.y - nr.y,
                                                xv.z - nr.z, xv.w - nr.w);
        } else {
            *(float4*)(dst + off) = nr;
        }
        if (write_hl) {
            ushort4 h;
            h.x = bf16rn(nr.x);
            h.y = bf16rn(nr.y);
            h.z = bf16rn(nr.z);
            h.w = bf16rn(nr.w);
            *(ushort4*)(rhi + off) = h;
        }
    }
    #pragma unroll
    for (int m = 1; m < 64; m <<= 1) lsum += __shfl_xor(lsum, m);
    if ((tid & 63) == 0)
        atomicAdd(loss_out, lsum * (1.0f / ((float)ROWS * (float)D_)));
}

// -------------------------------------------------------------------------
extern "C" void kernel_launch(void* const* d_in, const int* in_sizes, int n_in,
                              void* d_out, int out_size, void* d_ws, size_t ws_size,
                              hipStream_t stream) {
    const float* x  = (const float*)d_in[0];   // [B,N,D]
    const float* cb = (const float*)d_in[1];   // [Q,C,D]

    float* qout   = (float*)d_out;                                  // doubles as residual
    float* idx_f  = (float*)d_out + (size_t)ROWS * D_;              // [ROWS][Q_] as floats
    float* losses = idx_f + (size_t)ROWS * Q_;                      // [Q_]

    char* w = (char*)d_ws;
    unsigned short* cb_hi = (unsigned short*)w;                     // Q*C*D bf16 (8MB)
    float* cbT = (float*)(cb_hi + (size_t)Q_ * C_ * D_);            // Q*D*C f32 (16MB)
    float* norms = cbT + (size_t)Q_ * C_ * D_;                      // Q*C
    float* st_m1 = norms + Q_ * C_;                                 // 8*ROWS
    float* st_m2 = st_m1 + 8 * ROWS;
    int*   st_i1 = (int*)(st_m2 + 8 * ROWS);
    int*   idx_i = st_i1 + 8 * ROWS;                                // ROWS
    int*   list  = idx_i + ROWS;                                    // ROWS
    int*   nflag = list + ROWS;                                     // 8 counters + pad
    unsigned long long* pk = (unsigned long long*)(nflag + 64);     // ROWS u64 (256KB)
    unsigned short* res_hi = (unsigned short*)(pk + ROWS);          // ROWS*D (32MB)

    const size_t need = (size_t)((char*)(res_hi + (size_t)ROWS * D_) - w);
    const int preconv = (ws_size >= need) ? 1 : 0;

    hipMemsetAsync(losses, 0, Q_ * sizeof(float), stream);
    hipMemsetAsync(nflag, 0, 8 * sizeof(int), stream);   // all stages' counters
    conv_hi_kernel<<<Q_ * C_ * D_ / 1024, 256, 0, stream>>>(cb, cb_hi);
    code_norms_kernel<<<Q_ * C_ / 4, 256, 0, stream>>>(cb, norms);
    if (preconv) {
        conv_hi_kernel<<<(int)((size_t)ROWS * D_ / 1024), 256, 0, stream>>>(x, res_hi);
        cb_transpose_kernel<<<dim3(D_ / 64, C_ / 64, Q_), 256, 0, stream>>>(cb, cbT);
    }

    for (int q = 0; q < Q_; ++q) {
        const float* src = (q == 0) ? x : qout;
        const float* cb_s = cb + (size_t)q * C_ * D_;
        if (preconv)
            rvq_gemm_pipe_kernel<<<dim3(ROWS / 128, 4), 256, 0, stream>>>(
                res_hi, cb_hi + (size_t)q * C_ * D_,
                norms + (size_t)q * C_, st_m1, st_m2, st_i1);
        else
            rvq_gemm_fallback_kernel<<<dim3(ROWS / 128, 2), 256, 0, stream>>>(
                src, cb_hi + (size_t)q * C_ * D_,
                norms + (size_t)q * C_, st_m1, st_m2, st_i1);
        merge_kernel<<<ROWS / 256, 256, 0, stream>>>(
            st_m1, st_m2, st_i1, idx_i, idx_f, list, nflag + q, pk, q,
            preconv ? 8 : 4);
        if (preconv) {
            rescue_par_kernel<<<1024, 256, 0, stream>>>(
                src, cbT + (size_t)q * D_ * C_, norms + (size_t)q * C_,
                list, nflag + q, pk);
        } else {
            rescue_kernel<<<256, 256, 0, stream>>>(
                src, cb_s, norms + (size_t)q * C_, list, nflag + q, idx_i, idx_f, q);
        }
        update_kernel<<<ROWS / 64, 256, 0, stream>>>(
            src, qout, x, cb_s, idx_i, pk, idx_f, losses + q, res_hi,
            q, (q == Q_ - 1) ? 1 : 0, (preconv && q < Q_ - 1) ? 1 : 0, preconv);
    }
}